// Round 5
// baseline (501.885 us; speedup 1.0000x reference)
//
#include <hip/hip_runtime.h>
#include <hip/hip_fp16.h>

typedef _Float16 f16x8 __attribute__((ext_vector_type(8)));
typedef float f32x4 __attribute__((ext_vector_type(4)));
typedef unsigned short u16;

#define DN 128   // node in props
#define DE 32    // edge in props
#define LE 16    // latent edges (channels)
#define LN 64    // latent nodes
#define DOUT 128 // out props

__device__ inline u16 f2h(float f) { return __half_as_ushort(__float2half(f)); }
__device__ inline float h2f(u16 u) { return __half2float(__ushort_as_half(u)); }
__device__ inline unsigned pack2h(float lo, float hi) {
  return (unsigned)f2h(lo) | ((unsigned)f2h(hi) << 16);
}
__device__ inline void unp2(unsigned u, float& a, float& b) {
  __half2 p = *reinterpret_cast<__half2*>(&u);
  a = __half2float(__low2half(p));
  b = __half2float(__high2half(p));
}
// 8 fp16 packed in uint4 -> acc[0..7] += cf * val   (targets v_fma_mix)
__device__ inline void fma8h(float cf, uint4 h, float* acc) {
  float a, b;
  unp2(h.x, a, b); acc[0] = fmaf(cf, a, acc[0]); acc[1] = fmaf(cf, b, acc[1]);
  unp2(h.y, a, b); acc[2] = fmaf(cf, a, acc[2]); acc[3] = fmaf(cf, b, acc[3]);
  unp2(h.z, a, b); acc[4] = fmaf(cf, a, acc[4]); acc[5] = fmaf(cf, b, acc[5]);
  unp2(h.w, a, b); acc[6] = fmaf(cf, a, acc[6]); acc[7] = fmaf(cf, b, acc[7]);
}

// wh[epos[e], l] = fp16(relu(edge_attr[e,:] @ W_edge + b_edge)[l])  (CSR-ordered)
__global__ __launch_bounds__(256) void k_edge_props(const float* __restrict__ ea,
    const float* __restrict__ We, const float* __restrict__ be,
    const int* __restrict__ epos, u16* __restrict__ wh, int E) {
  int e = blockIdx.x * 256 + threadIdx.x;
  if (e >= E) return;
  const float4* a4 = (const float4*)(ea + (size_t)e * DE);
  float a[DE];
#pragma unroll
  for (int j = 0; j < DE / 4; ++j) {
    float4 v = a4[j];
    a[4*j] = v.x; a[4*j+1] = v.y; a[4*j+2] = v.z; a[4*j+3] = v.w;
  }
  float acc[LE];
#pragma unroll
  for (int l = 0; l < LE; ++l) acc[l] = be[l];
#pragma unroll
  for (int k = 0; k < DE; ++k) {
    float av = a[k];
#pragma unroll
    for (int l = 0; l < LE; ++l) acc[l] = fmaf(av, We[k * LE + l], acc[l]);
  }
  uint4 o0, o1;
  o0.x = pack2h(fmaxf(acc[0], 0.f), fmaxf(acc[1], 0.f));
  o0.y = pack2h(fmaxf(acc[2], 0.f), fmaxf(acc[3], 0.f));
  o0.z = pack2h(fmaxf(acc[4], 0.f), fmaxf(acc[5], 0.f));
  o0.w = pack2h(fmaxf(acc[6], 0.f), fmaxf(acc[7], 0.f));
  o1.x = pack2h(fmaxf(acc[8], 0.f), fmaxf(acc[9], 0.f));
  o1.y = pack2h(fmaxf(acc[10], 0.f), fmaxf(acc[11], 0.f));
  o1.z = pack2h(fmaxf(acc[12], 0.f), fmaxf(acc[13], 0.f));
  o1.w = pack2h(fmaxf(acc[14], 0.f), fmaxf(acc[15], 0.f));
  uint4* o4 = (uint4*)(wh + (size_t)epos[e] * LE);
  o4[0] = o0; o4[1] = o1;
}

// Pack fp32 W[K,NCOL] into fp16 MFMA-B fragments:
// dst[((nt*KT+kt)*64+lane)*8+i] = W[kt*32+(lane>>4)*8+i][nt*16+(lane&15)]
__global__ __launch_bounds__(256) void k_packb(const float* __restrict__ W,
                                               u16* __restrict__ Bp, int K, int NCOL) {
  int NT = NCOL >> 4, KT = K >> 5;
  int total = NT * KT * 64;
  int idx = blockIdx.x * 256 + threadIdx.x;
  if (idx >= total) return;
  int lane = idx & 63;
  int rest = idx >> 6;
  int kt = rest % KT, nt = rest / KT;
  int col = nt * 16 + (lane & 15);
  int kb = kt * 32 + (lane >> 4) * 8;
  u16* dst = Bp + (size_t)idx * 8;
#pragma unroll
  for (int i = 0; i < 8; ++i) dst[i] = f2h(W[(size_t)(kb + i) * NCOL + col]);
}

__global__ __launch_bounds__(256) void k_count(const int* __restrict__ ei,
                                               int* __restrict__ cnt, int E) {
  int e = blockIdx.x * 256 + threadIdx.x;
  if (e < E) atomicAdd(&cnt[ei[E + e]], 1);
}

// single-block exclusive scan over cnt[0..N) -> offs[0..N]
__global__ __launch_bounds__(1024) void k_scan(const int* __restrict__ cnt,
                                               int* __restrict__ offs, int N) {
  __shared__ int wsum[16];
  int t = threadIdx.x;
  int chunk = (N + 1023) >> 10;
  int s0 = t * chunk;
  int s1 = min(s0 + chunk, N);
  int s = 0;
  for (int i = s0; i < s1; ++i) s += cnt[i];
  int lane = t & 63, wid = t >> 6;
  int v = s;
#pragma unroll
  for (int d = 1; d < 64; d <<= 1) {
    int u = __shfl_up(v, d);
    if (lane >= d) v += u;
  }
  if (lane == 63) wsum[wid] = v;
  __syncthreads();
  if (t == 0) {
    int run = 0;
    for (int w = 0; w < 16; ++w) { int xv = wsum[w]; wsum[w] = run; run += xv; }
  }
  __syncthreads();
  int run = v - s + wsum[wid];  // exclusive prefix for this thread
  for (int i = s0; i < s1; ++i) { offs[i] = run; run += cnt[i]; }
  if (s1 == N && s0 < N) offs[N] = run;
}

// epos[e] = CSR slot of edge e; src[slot] = source node of that edge
__global__ __launch_bounds__(256) void k_fill(const int* __restrict__ ei,
    int* __restrict__ cur, const int* __restrict__ offs,
    int* __restrict__ epos, int* __restrict__ src, int E) {
  int e = blockIdx.x * 256 + threadIdx.x;
  if (e >= E) return;
  int c = ei[E + e];
  int p = atomicAdd(&cur[c], 1);
  int pos = offs[c] + p;
  epos[e] = pos;
  src[pos] = ei[e];
}

// dinv[n,l] = rsqrt(1 + sum over CSR segment of wh[i,l])
__global__ __launch_bounds__(256) void k_dinv(const u16* __restrict__ wh,
    const int* __restrict__ offs, float* __restrict__ dinv, int N) {
  int t = threadIdx.x;
  int n = blockIdx.x * 16 + (t >> 4);
  int l = t & 15;
  if (n >= N) return;
  int i0 = offs[n], i1 = offs[n + 1];
  float s = 1.0f;  // self loop weight
  for (int i = i0; i < i1; ++i) s += h2f(wh[(size_t)i * LE + l]);
  dinv[(size_t)n * LE + l] = rsqrtf(s);
}

// pre-fold source normalization: wsc[pos,l] = fp16(wh[pos,l] * dinv[src[pos],l])
__global__ __launch_bounds__(256) void k_wsc(const u16* __restrict__ wh,
    const int* __restrict__ src, const float* __restrict__ dinv,
    u16* __restrict__ wsc, int T) {
  int pos = blockIdx.x * 256 + threadIdx.x;
  if (pos >= T) return;
  int s = src[pos];
  const uint4* w4 = (const uint4*)(wh + (size_t)pos * LE);
  const float4* d4 = (const float4*)(dinv + (size_t)s * LE);
  uint4 wa = w4[0], wb2 = w4[1];
  float4 d0 = d4[0], d1 = d4[1], d2 = d4[2], d3 = d4[3];
  float a, b;
  uint4 o0, o1;
  unp2(wa.x, a, b);  o0.x = pack2h(a * d0.x, b * d0.y);
  unp2(wa.y, a, b);  o0.y = pack2h(a * d0.z, b * d0.w);
  unp2(wa.z, a, b);  o0.z = pack2h(a * d1.x, b * d1.y);
  unp2(wa.w, a, b);  o0.w = pack2h(a * d1.z, b * d1.w);
  unp2(wb2.x, a, b); o1.x = pack2h(a * d2.x, b * d2.y);
  unp2(wb2.y, a, b); o1.y = pack2h(a * d2.z, b * d2.w);
  unp2(wb2.z, a, b); o1.z = pack2h(a * d3.x, b * d3.y);
  unp2(wb2.w, a, b); o1.w = pack2h(a * d3.z, b * d3.w);
  uint4* o4 = (uint4*)(wsc + (size_t)pos * LE);
  o4[0] = o0; o4[1] = o1;
}

// C[M,NCOL] = A[M,K] @ Bpacked(fp16) (+bias, relu if FIN)
// A fp32 converted in-register (AF32) or fp16; out fp32 or fp16 (OUT16)
template <int K, int NCOL, bool FIN, bool AF32, bool OUT16>
__global__ __launch_bounds__(256) void k_gemm(const void* __restrict__ Av,
    const u16* __restrict__ Bp, const float* __restrict__ bias,
    void* __restrict__ outv, int M) {
  constexpr int NT = NCOL / 16;
  constexpr int KT = K / 32;
  const u16* A16 = (const u16*)Av;
  const float* A32 = (const float*)Av;
  int lane = threadIdx.x & 63;
  int wid = threadIdx.x >> 6;
  int m0 = blockIdx.x * 128 + wid * 32;
  f32x4 acc[2][NT];
#pragma unroll
  for (int mt = 0; mt < 2; ++mt)
#pragma unroll
    for (int nt = 0; nt < NT; ++nt) {
      acc[mt][nt][0] = 0.f; acc[mt][nt][1] = 0.f;
      acc[mt][nt][2] = 0.f; acc[mt][nt][3] = 0.f;
    }
  int r0 = m0 + (lane & 15);
  int r1 = r0 + 16;
  bool v0 = r0 < M, v1 = r1 < M;
  int ko = (lane >> 4) * 8;
#pragma unroll 4
  for (int kt = 0; kt < KT; ++kt) {
    f16x8 a0, a1;
#pragma unroll
    for (int i = 0; i < 8; ++i) { a0[i] = (_Float16)0.f; a1[i] = (_Float16)0.f; }
    if constexpr (AF32) {
      if (v0) {
        const float4* p4 = (const float4*)(A32 + (size_t)r0 * K + ko + kt * 32);
        float4 u0 = p4[0], u1 = p4[1];
        a0[0]=(_Float16)u0.x; a0[1]=(_Float16)u0.y; a0[2]=(_Float16)u0.z; a0[3]=(_Float16)u0.w;
        a0[4]=(_Float16)u1.x; a0[5]=(_Float16)u1.y; a0[6]=(_Float16)u1.z; a0[7]=(_Float16)u1.w;
      }
      if (v1) {
        const float4* p4 = (const float4*)(A32 + (size_t)r1 * K + ko + kt * 32);
        float4 u0 = p4[0], u1 = p4[1];
        a1[0]=(_Float16)u0.x; a1[1]=(_Float16)u0.y; a1[2]=(_Float16)u0.z; a1[3]=(_Float16)u0.w;
        a1[4]=(_Float16)u1.x; a1[5]=(_Float16)u1.y; a1[6]=(_Float16)u1.z; a1[7]=(_Float16)u1.w;
      }
    } else {
      if (v0) a0 = *(const f16x8*)(A16 + (size_t)r0 * K + ko + kt * 32);
      if (v1) a1 = *(const f16x8*)(A16 + (size_t)r1 * K + ko + kt * 32);
    }
#pragma unroll
    for (int nt = 0; nt < NT; ++nt) {
      f16x8 b = *(const f16x8*)(Bp + ((size_t)(nt * KT + kt) * 64 + lane) * 8);
      acc[0][nt] = __builtin_amdgcn_mfma_f32_16x16x32_f16(a0, b, acc[0][nt], 0, 0, 0);
      acc[1][nt] = __builtin_amdgcn_mfma_f32_16x16x32_f16(a1, b, acc[1][nt], 0, 0, 0);
    }
  }
  int col0 = lane & 15;
#pragma unroll
  for (int mt = 0; mt < 2; ++mt) {
    int rb = m0 + mt * 16 + ((lane >> 4) << 2);
#pragma unroll
    for (int nt = 0; nt < NT; ++nt) {
      int c = nt * 16 + col0;
      float bb = FIN ? bias[c] : 0.f;
#pragma unroll
      for (int r = 0; r < 4; ++r) {
        int row = rb + r;
        if (row < M) {
          float vv = acc[mt][nt][r] + bb;
          if (FIN) vv = fmaxf(vv, 0.f);
          if constexpr (OUT16) ((u16*)outv)[(size_t)row * NCOL + c] = f2h(vv);
          else ((float*)outv)[(size_t)row * NCOL + c] = vv;
        }
      }
    }
  }
}

// Fused: GCN aggregation (gather) -> feats row in LDS (fp16) -> MFMA output MLP
// block = 8 nodes (4 waves x 2 nodes); lane: l = lane&15 (channel), g = lane>>4
// LDS: 8 rows x 2064 B (pad 16) + XOR swizzle ((l&7)<<4) on within-row byte offset
// Phase 2: A-frag rows via (lane&7) -> rows 8..15 duplicate 0..7; stores masked.
__global__ __launch_bounds__(256, 8) void k_fused(const int* __restrict__ src,
    const u16* __restrict__ wsc, const float* __restrict__ dinv,
    const u16* __restrict__ xwh, const float* __restrict__ bgcn,
    const int* __restrict__ offs, const u16* __restrict__ WnP,
    const float* __restrict__ bn, float* __restrict__ y, int N) {
  __shared__ char Sm[8 * 2064];
  int tid = threadIdx.x;
  int wid = tid >> 6, lane = tid & 63;
  int l = lane & 15, g = lane >> 4;
  int nblk = blockIdx.x * 8;
  // ---- gather phase: 2 nodes per wave ----
  for (int q = 0; q < 2; ++q) {
    int r = wid * 2 + q;
    int n = nblk + r;
    bool valid = n < N;
    float acc[16];
#pragma unroll
    for (int j = 0; j < 16; ++j) acc[j] = 0.f;
    float dn = 1.f;
    if (valid) {
      dn = dinv[(size_t)n * LE + l];
      int i0 = offs[n], i1 = offs[n + 1];
      int sA = (i0 < i1) ? src[i0] : 0;
#pragma unroll 2
      for (int i = i0; i < i1; ++i) {
        int s = sA;
        float cf = h2f(wsc[(size_t)i * LE + l]);
        const uint4* xr = (const uint4*)(xwh + (size_t)s * LN + g * 16);
        uint4 h0 = xr[0], h1 = xr[1];
        if (i + 1 < i1) sA = src[i + 1];
        fma8h(cf, h0, acc);
        fma8h(cf, h1, acc + 8);
      }
    }
    // epilogue -> LDS (fp16)
    float dn2 = dn * dn;
    int nn = valid ? n : 0;
    const uint4* xs = (const uint4*)(xwh + (size_t)nn * LN + g * 16);
    uint4 m0 = xs[0], m1 = xs[1];
    const float4* bg4 = (const float4*)(bgcn + g * 16);
    float4 b0 = bg4[0], b1 = bg4[1], b2 = bg4[2], b3 = bg4[3];
    float xv[16];
    unp2(m0.x, xv[0], xv[1]);   unp2(m0.y, xv[2], xv[3]);
    unp2(m0.z, xv[4], xv[5]);   unp2(m0.w, xv[6], xv[7]);
    unp2(m1.x, xv[8], xv[9]);   unp2(m1.y, xv[10], xv[11]);
    unp2(m1.z, xv[12], xv[13]); unp2(m1.w, xv[14], xv[15]);
    float bgv[16] = {b0.x,b0.y,b0.z,b0.w,b1.x,b1.y,b1.z,b1.w,
                     b2.x,b2.y,b2.z,b2.w,b3.x,b3.y,b3.z,b3.w};
    float ov[16];
#pragma unroll
    for (int j = 0; j < 16; ++j) ov[j] = bgv[j] + dn * acc[j] + dn2 * xv[j];
    uint4 o0, o1;
    o0.x = pack2h(ov[0], ov[1]);   o0.y = pack2h(ov[2], ov[3]);
    o0.z = pack2h(ov[4], ov[5]);   o0.w = pack2h(ov[6], ov[7]);
    o1.x = pack2h(ov[8], ov[9]);   o1.y = pack2h(ov[10], ov[11]);
    o1.z = pack2h(ov[12], ov[13]); o1.w = pack2h(ov[14], ov[15]);
    int off = l * 128 + g * 32;  // byte offset within feats row
    int swz = (l & 7) << 4;
    char* rowp = Sm + r * 2064;
    *(uint4*)(rowp + (off ^ swz)) = o0;
    *(uint4*)(rowp + ((off + 16) ^ swz)) = o1;
  }
  __syncthreads();
  // ---- MFMA phase: y[8,128] = S[8,1024] @ Wn (rows 8..15 duplicated) ----
  f32x4 acc2[2];
#pragma unroll
  for (int t = 0; t < 2; ++t) {
    acc2[t][0] = 0.f; acc2[t][1] = 0.f; acc2[t][2] = 0.f; acc2[t][3] = 0.f;
  }
  const char* arow = Sm + (lane & 7) * 2064;
#pragma unroll 8
  for (int kt = 0; kt < 32; ++kt) {
    int aoff = kt * 64 + g * 16;
    int key = ((aoff >> 7) & 7) << 4;
    f16x8 a = *(const f16x8*)(arow + (aoff ^ key));
    f16x8 bA = *(const f16x8*)(WnP + ((size_t)((wid * 2 + 0) * 32 + kt) * 64 + lane) * 8);
    f16x8 bB = *(const f16x8*)(WnP + ((size_t)((wid * 2 + 1) * 32 + kt) * 64 + lane) * 8);
    acc2[0] = __builtin_amdgcn_mfma_f32_16x16x32_f16(a, bA, acc2[0], 0, 0, 0);
    acc2[1] = __builtin_amdgcn_mfma_f32_16x16x32_f16(a, bB, acc2[1], 0, 0, 0);
  }
  int col0 = lane & 15;
  int rloc = (lane >> 4) * 4;
#pragma unroll
  for (int t = 0; t < 2; ++t) {
    int c = (wid * 2 + t) * 16 + col0;
    float bb = bn[c];
#pragma unroll
    for (int rr = 0; rr < 4; ++rr) {
      int r = rloc + rr;
      int row = nblk + r;
      if (r < 8 && row < N) y[(size_t)row * DOUT + c] = fmaxf(acc2[t][rr] + bb, 0.f);
    }
  }
}

extern "C" void kernel_launch(void* const* d_in, const int* in_sizes, int n_in,
                              void* d_out, int out_size, void* d_ws, size_t ws_size,
                              hipStream_t stream) {
  const float* x  = (const float*)d_in[0];
  const int*   ei = (const int*)d_in[1];
  const float* ea = (const float*)d_in[2];
  const float* Wg = (const float*)d_in[3];
  const float* bg = (const float*)d_in[4];
  const float* We = (const float*)d_in[5];
  const float* be = (const float*)d_in[6];
  const float* Wn = (const float*)d_in[7];
  const float* bn = (const float*)d_in[8];
  float* outp = (float*)d_out;
  int N = in_sizes[0] / DN;  // 50000
  int E = in_sizes[1] / 2;   // 800000

  char* p = (char*)d_ws;
  auto carve = [&](size_t bytes) {
    char* r = p;
    p += (bytes + 255) & ~(size_t)255;
    return (void*)r;
  };
  u16*   wh    = (u16*)carve((size_t)E * LE * 2);    // CSR-ordered latent weights, fp16
  u16*   wsc   = (u16*)carve((size_t)E * LE * 2);    // pre-normalized weights, fp16
  u16*   xwh   = (u16*)carve((size_t)N * LN * 2);    // xW in fp16
  float* dinv  = (float*)carve((size_t)N * LE * 4);
  u16*   WnP   = (u16*)carve((size_t)(LE * LN) * DOUT * 2);
  u16*   WgP   = (u16*)carve((size_t)DN * LN * 2);
  int*   offs  = (int*)carve((size_t)(N + 1) * 4);
  int*   cnt   = (int*)carve((size_t)N * 4);
  int*   cur   = (int*)carve((size_t)N * 4);
  int*   src   = (int*)carve((size_t)E * 4);
  int*   epos  = (int*)carve((size_t)E * 4);

  hipMemsetAsync(cnt, 0, (size_t)N * 4, stream);
  hipMemsetAsync(cur, 0, (size_t)N * 4, stream);

  // CSR build
  k_count<<<(E + 255) / 256, 256, 0, stream>>>(ei, cnt, E);
  k_scan<<<1, 1024, 0, stream>>>(cnt, offs, N);
  k_fill<<<(E + 255) / 256, 256, 0, stream>>>(ei, cur, offs, epos, src, E);
  // edge MLP directly into CSR order (fp16)
  k_edge_props<<<(E + 255) / 256, 256, 0, stream>>>(ea, We, be, epos, wh, E);
  // node GEMM path (independent of edges): xW in fp16
  k_packb<<<(((DN / 32) * (LN / 16) * 64) + 255) / 256, 256, 0, stream>>>(Wg, WgP, DN, LN);
  k_packb<<<((((LE * LN) / 32) * (DOUT / 16) * 64) + 255) / 256, 256, 0, stream>>>(Wn, WnP, LE * LN, DOUT);
  k_gemm<DN, LN, false, true, true><<<(N + 127) / 128, 256, 0, stream>>>(x, WgP, nullptr, xwh, N);
  // weighted in-degree normalization, then pre-fold dinv[src] into weights
  k_dinv<<<(N + 15) / 16, 256, 0, stream>>>(wh, offs, dinv, N);
  k_wsc<<<(E + 255) / 256, 256, 0, stream>>>(wh, src, dinv, wsc, E);
  // fused aggregation + output MLP
  k_fused<<<(N + 7) / 8, 256, 0, stream>>>(src, wsc, dinv, xwh, bg, offs, WnP, bn, outp, N);
}

// Round 6
// 433.535 us; speedup vs baseline: 1.1577x; 1.1577x over previous
//
#include <hip/hip_runtime.h>
#include <hip/hip_fp16.h>

typedef _Float16 f16x8 __attribute__((ext_vector_type(8)));
typedef float f32x4 __attribute__((ext_vector_type(4)));
typedef unsigned short u16;

#define DN 128   // node in props
#define DE 32    // edge in props
#define LE 16    // latent edges (channels)
#define LN 64    // latent nodes
#define DOUT 128 // out props

__device__ inline u16 f2h(float f) { return __half_as_ushort(__float2half(f)); }
__device__ inline float h2f(u16 u) { return __half2float(__ushort_as_half(u)); }
__device__ inline unsigned pack2h(float lo, float hi) {
  return (unsigned)f2h(lo) | ((unsigned)f2h(hi) << 16);
}
__device__ inline void unp2(unsigned u, float& a, float& b) {
  __half2 p = *reinterpret_cast<__half2*>(&u);
  a = __half2float(__low2half(p));
  b = __half2float(__high2half(p));
}
// 8 fp16 packed in uint4 -> acc[0..7] += cf * val   (targets v_fma_mix)
__device__ inline void fma8h(float cf, uint4 h, float* acc) {
  float a, b;
  unp2(h.x, a, b); acc[0] = fmaf(cf, a, acc[0]); acc[1] = fmaf(cf, b, acc[1]);
  unp2(h.y, a, b); acc[2] = fmaf(cf, a, acc[2]); acc[3] = fmaf(cf, b, acc[3]);
  unp2(h.z, a, b); acc[4] = fmaf(cf, a, acc[4]); acc[5] = fmaf(cf, b, acc[5]);
  unp2(h.w, a, b); acc[6] = fmaf(cf, a, acc[6]); acc[7] = fmaf(cf, b, acc[7]);
}

// wh[epos[e], l] = fp16(relu(edge_attr[e,:] @ W_edge + b_edge)[l])  (CSR-ordered)
__global__ __launch_bounds__(256) void k_edge_props(const float* __restrict__ ea,
    const float* __restrict__ We, const float* __restrict__ be,
    const int* __restrict__ epos, u16* __restrict__ wh, int E) {
  int e = blockIdx.x * 256 + threadIdx.x;
  if (e >= E) return;
  const float4* a4 = (const float4*)(ea + (size_t)e * DE);
  float a[DE];
#pragma unroll
  for (int j = 0; j < DE / 4; ++j) {
    float4 v = a4[j];
    a[4*j] = v.x; a[4*j+1] = v.y; a[4*j+2] = v.z; a[4*j+3] = v.w;
  }
  float acc[LE];
#pragma unroll
  for (int l = 0; l < LE; ++l) acc[l] = be[l];
#pragma unroll
  for (int k = 0; k < DE; ++k) {
    float av = a[k];
#pragma unroll
    for (int l = 0; l < LE; ++l) acc[l] = fmaf(av, We[k * LE + l], acc[l]);
  }
  uint4 o0, o1;
  o0.x = pack2h(fmaxf(acc[0], 0.f), fmaxf(acc[1], 0.f));
  o0.y = pack2h(fmaxf(acc[2], 0.f), fmaxf(acc[3], 0.f));
  o0.z = pack2h(fmaxf(acc[4], 0.f), fmaxf(acc[5], 0.f));
  o0.w = pack2h(fmaxf(acc[6], 0.f), fmaxf(acc[7], 0.f));
  o1.x = pack2h(fmaxf(acc[8], 0.f), fmaxf(acc[9], 0.f));
  o1.y = pack2h(fmaxf(acc[10], 0.f), fmaxf(acc[11], 0.f));
  o1.z = pack2h(fmaxf(acc[12], 0.f), fmaxf(acc[13], 0.f));
  o1.w = pack2h(fmaxf(acc[14], 0.f), fmaxf(acc[15], 0.f));
  uint4* o4 = (uint4*)(wh + (size_t)epos[e] * LE);
  o4[0] = o0; o4[1] = o1;
}

// Pack fp32 W[K,NCOL] into fp16 MFMA-B fragments:
// dst[((nt*KT+kt)*64+lane)*8+i] = W[kt*32+(lane>>4)*8+i][nt*16+(lane&15)]
__global__ __launch_bounds__(256) void k_packb(const float* __restrict__ W,
                                               u16* __restrict__ Bp, int K, int NCOL) {
  int NT = NCOL >> 4, KT = K >> 5;
  int total = NT * KT * 64;
  int idx = blockIdx.x * 256 + threadIdx.x;
  if (idx >= total) return;
  int lane = idx & 63;
  int rest = idx >> 6;
  int kt = rest % KT, nt = rest / KT;
  int col = nt * 16 + (lane & 15);
  int kb = kt * 32 + (lane >> 4) * 8;
  u16* dst = Bp + (size_t)idx * 8;
#pragma unroll
  for (int i = 0; i < 8; ++i) dst[i] = f2h(W[(size_t)(kb + i) * NCOL + col]);
}

__global__ __launch_bounds__(256) void k_count(const int* __restrict__ ei,
                                               int* __restrict__ cnt, int E) {
  int e = blockIdx.x * 256 + threadIdx.x;
  if (e < E) atomicAdd(&cnt[ei[E + e]], 1);
}

// single-block exclusive scan over cnt[0..N) -> offs[0..N]
__global__ __launch_bounds__(1024) void k_scan(const int* __restrict__ cnt,
                                               int* __restrict__ offs, int N) {
  __shared__ int wsum[16];
  int t = threadIdx.x;
  int chunk = (N + 1023) >> 10;
  int s0 = t * chunk;
  int s1 = min(s0 + chunk, N);
  int s = 0;
  for (int i = s0; i < s1; ++i) s += cnt[i];
  int lane = t & 63, wid = t >> 6;
  int v = s;
#pragma unroll
  for (int d = 1; d < 64; d <<= 1) {
    int u = __shfl_up(v, d);
    if (lane >= d) v += u;
  }
  if (lane == 63) wsum[wid] = v;
  __syncthreads();
  if (t == 0) {
    int run = 0;
    for (int w = 0; w < 16; ++w) { int xv = wsum[w]; wsum[w] = run; run += xv; }
  }
  __syncthreads();
  int run = v - s + wsum[wid];  // exclusive prefix for this thread
  for (int i = s0; i < s1; ++i) { offs[i] = run; run += cnt[i]; }
  if (s1 == N && s0 < N) offs[N] = run;
}

// epos[e] = CSR slot of edge e; src[slot] = source node of that edge
__global__ __launch_bounds__(256) void k_fill(const int* __restrict__ ei,
    int* __restrict__ cur, const int* __restrict__ offs,
    int* __restrict__ epos, int* __restrict__ src, int E) {
  int e = blockIdx.x * 256 + threadIdx.x;
  if (e >= E) return;
  int c = ei[E + e];
  int p = atomicAdd(&cur[c], 1);
  int pos = offs[c] + p;
  epos[e] = pos;
  src[pos] = ei[e];
}

// dinv[n,l] = rsqrt(1 + sum over CSR segment of wh[i,l])
__global__ __launch_bounds__(256) void k_dinv(const u16* __restrict__ wh,
    const int* __restrict__ offs, float* __restrict__ dinv, int N) {
  int t = threadIdx.x;
  int n = blockIdx.x * 16 + (t >> 4);
  int l = t & 15;
  if (n >= N) return;
  int i0 = offs[n], i1 = offs[n + 1];
  float s = 1.0f;  // self loop weight
  for (int i = i0; i < i1; ++i) s += h2f(wh[(size_t)i * LE + l]);
  dinv[(size_t)n * LE + l] = rsqrtf(s);
}

// pre-fold source normalization: wsc[pos,l] = fp16(wh[pos,l] * dinv[src[pos],l])
__global__ __launch_bounds__(256) void k_wsc(const u16* __restrict__ wh,
    const int* __restrict__ src, const float* __restrict__ dinv,
    u16* __restrict__ wsc, int T) {
  int pos = blockIdx.x * 256 + threadIdx.x;
  if (pos >= T) return;
  int s = src[pos];
  const uint4* w4 = (const uint4*)(wh + (size_t)pos * LE);
  const float4* d4 = (const float4*)(dinv + (size_t)s * LE);
  uint4 wa = w4[0], wb2 = w4[1];
  float4 d0 = d4[0], d1 = d4[1], d2 = d4[2], d3 = d4[3];
  float a, b;
  uint4 o0, o1;
  unp2(wa.x, a, b);  o0.x = pack2h(a * d0.x, b * d0.y);
  unp2(wa.y, a, b);  o0.y = pack2h(a * d0.z, b * d0.w);
  unp2(wa.z, a, b);  o0.z = pack2h(a * d1.x, b * d1.y);
  unp2(wa.w, a, b);  o0.w = pack2h(a * d1.z, b * d1.w);
  unp2(wb2.x, a, b); o1.x = pack2h(a * d2.x, b * d2.y);
  unp2(wb2.y, a, b); o1.y = pack2h(a * d2.z, b * d2.w);
  unp2(wb2.z, a, b); o1.z = pack2h(a * d3.x, b * d3.y);
  unp2(wb2.w, a, b); o1.w = pack2h(a * d3.z, b * d3.w);
  uint4* o4 = (uint4*)(wsc + (size_t)pos * LE);
  o4[0] = o0; o4[1] = o1;
}

// C[M,NCOL] = A[M,K] @ Bpacked(fp16) (+bias, relu if FIN)
// A fp32 converted in-register (AF32) or fp16; out fp32 or fp16 (OUT16)
template <int K, int NCOL, bool FIN, bool AF32, bool OUT16>
__global__ __launch_bounds__(256) void k_gemm(const void* __restrict__ Av,
    const u16* __restrict__ Bp, const float* __restrict__ bias,
    void* __restrict__ outv, int M) {
  constexpr int NT = NCOL / 16;
  constexpr int KT = K / 32;
  const u16* A16 = (const u16*)Av;
  const float* A32 = (const float*)Av;
  int lane = threadIdx.x & 63;
  int wid = threadIdx.x >> 6;
  int m0 = blockIdx.x * 128 + wid * 32;
  f32x4 acc[2][NT];
#pragma unroll
  for (int mt = 0; mt < 2; ++mt)
#pragma unroll
    for (int nt = 0; nt < NT; ++nt) {
      acc[mt][nt][0] = 0.f; acc[mt][nt][1] = 0.f;
      acc[mt][nt][2] = 0.f; acc[mt][nt][3] = 0.f;
    }
  int r0 = m0 + (lane & 15);
  int r1 = r0 + 16;
  bool v0 = r0 < M, v1 = r1 < M;
  int ko = (lane >> 4) * 8;
#pragma unroll 4
  for (int kt = 0; kt < KT; ++kt) {
    f16x8 a0, a1;
#pragma unroll
    for (int i = 0; i < 8; ++i) { a0[i] = (_Float16)0.f; a1[i] = (_Float16)0.f; }
    if constexpr (AF32) {
      if (v0) {
        const float4* p4 = (const float4*)(A32 + (size_t)r0 * K + ko + kt * 32);
        float4 u0 = p4[0], u1 = p4[1];
        a0[0]=(_Float16)u0.x; a0[1]=(_Float16)u0.y; a0[2]=(_Float16)u0.z; a0[3]=(_Float16)u0.w;
        a0[4]=(_Float16)u1.x; a0[5]=(_Float16)u1.y; a0[6]=(_Float16)u1.z; a0[7]=(_Float16)u1.w;
      }
      if (v1) {
        const float4* p4 = (const float4*)(A32 + (size_t)r1 * K + ko + kt * 32);
        float4 u0 = p4[0], u1 = p4[1];
        a1[0]=(_Float16)u0.x; a1[1]=(_Float16)u0.y; a1[2]=(_Float16)u0.z; a1[3]=(_Float16)u0.w;
        a1[4]=(_Float16)u1.x; a1[5]=(_Float16)u1.y; a1[6]=(_Float16)u1.z; a1[7]=(_Float16)u1.w;
      }
    } else {
      if (v0) a0 = *(const f16x8*)(A16 + (size_t)r0 * K + ko + kt * 32);
      if (v1) a1 = *(const f16x8*)(A16 + (size_t)r1 * K + ko + kt * 32);
    }
#pragma unroll
    for (int nt = 0; nt < NT; ++nt) {
      f16x8 b = *(const f16x8*)(Bp + ((size_t)(nt * KT + kt) * 64 + lane) * 8);
      acc[0][nt] = __builtin_amdgcn_mfma_f32_16x16x32_f16(a0, b, acc[0][nt], 0, 0, 0);
      acc[1][nt] = __builtin_amdgcn_mfma_f32_16x16x32_f16(a1, b, acc[1][nt], 0, 0, 0);
    }
  }
  int col0 = lane & 15;
#pragma unroll
  for (int mt = 0; mt < 2; ++mt) {
    int rb = m0 + mt * 16 + ((lane >> 4) << 2);
#pragma unroll
    for (int nt = 0; nt < NT; ++nt) {
      int c = nt * 16 + col0;
      float bb = FIN ? bias[c] : 0.f;
#pragma unroll
      for (int r = 0; r < 4; ++r) {
        int row = rb + r;
        if (row < M) {
          float vv = acc[mt][nt][r] + bb;
          if (FIN) vv = fmaxf(vv, 0.f);
          if constexpr (OUT16) ((u16*)outv)[(size_t)row * NCOL + c] = f2h(vv);
          else ((float*)outv)[(size_t)row * NCOL + c] = vv;
        }
      }
    }
  }
}

// Fused: GCN aggregation (gather) -> feats row in LDS (fp16) -> MFMA output MLP
// block = 8 nodes (4 waves x 2 nodes); lane: l = lane&15 (channel), g = lane>>4
// LDS: 8 rows x 2064 B (pad 16) + XOR swizzle ((l&7)<<4) on within-row byte offset
// Phase 2: A-frag rows via (lane&7) -> rows 8..15 duplicate 0..7; stores masked.
// NOTE: no min-waves clause — round-5's (256,8) forced VGPR=32 and spilled acc
// to scratch (WRITE_SIZE 25->413 MB). ~52-64 VGPR still allows 8 waves/SIMD.
__global__ __launch_bounds__(256) void k_fused(const int* __restrict__ src,
    const u16* __restrict__ wsc, const float* __restrict__ dinv,
    const u16* __restrict__ xwh, const float* __restrict__ bgcn,
    const int* __restrict__ offs, const u16* __restrict__ WnP,
    const float* __restrict__ bn, float* __restrict__ y, int N) {
  __shared__ char Sm[8 * 2064];
  int tid = threadIdx.x;
  int wid = tid >> 6, lane = tid & 63;
  int l = lane & 15, g = lane >> 4;
  int nblk = blockIdx.x * 8;
  // ---- gather phase: 2 nodes per wave ----
  for (int q = 0; q < 2; ++q) {
    int r = wid * 2 + q;
    int n = nblk + r;
    bool valid = n < N;
    float acc[16];
#pragma unroll
    for (int j = 0; j < 16; ++j) acc[j] = 0.f;
    float dn = 1.f;
    if (valid) {
      dn = dinv[(size_t)n * LE + l];
      int i0 = offs[n], i1 = offs[n + 1];
      int sA = (i0 < i1) ? src[i0] : 0;
#pragma unroll 2
      for (int i = i0; i < i1; ++i) {
        int s = sA;
        float cf = h2f(wsc[(size_t)i * LE + l]);
        const uint4* xr = (const uint4*)(xwh + (size_t)s * LN + g * 16);
        uint4 h0 = xr[0], h1 = xr[1];
        if (i + 1 < i1) sA = src[i + 1];
        fma8h(cf, h0, acc);
        fma8h(cf, h1, acc + 8);
      }
    }
    // epilogue -> LDS (fp16)
    float dn2 = dn * dn;
    int nn = valid ? n : 0;
    const uint4* xs = (const uint4*)(xwh + (size_t)nn * LN + g * 16);
    uint4 m0 = xs[0], m1 = xs[1];
    const float4* bg4 = (const float4*)(bgcn + g * 16);
    float4 b0 = bg4[0], b1 = bg4[1], b2 = bg4[2], b3 = bg4[3];
    float xv[16];
    unp2(m0.x, xv[0], xv[1]);   unp2(m0.y, xv[2], xv[3]);
    unp2(m0.z, xv[4], xv[5]);   unp2(m0.w, xv[6], xv[7]);
    unp2(m1.x, xv[8], xv[9]);   unp2(m1.y, xv[10], xv[11]);
    unp2(m1.z, xv[12], xv[13]); unp2(m1.w, xv[14], xv[15]);
    float bgv[16] = {b0.x,b0.y,b0.z,b0.w,b1.x,b1.y,b1.z,b1.w,
                     b2.x,b2.y,b2.z,b2.w,b3.x,b3.y,b3.z,b3.w};
    float ov[16];
#pragma unroll
    for (int j = 0; j < 16; ++j) ov[j] = bgv[j] + dn * acc[j] + dn2 * xv[j];
    uint4 o0, o1;
    o0.x = pack2h(ov[0], ov[1]);   o0.y = pack2h(ov[2], ov[3]);
    o0.z = pack2h(ov[4], ov[5]);   o0.w = pack2h(ov[6], ov[7]);
    o1.x = pack2h(ov[8], ov[9]);   o1.y = pack2h(ov[10], ov[11]);
    o1.z = pack2h(ov[12], ov[13]); o1.w = pack2h(ov[14], ov[15]);
    int off = l * 128 + g * 32;  // byte offset within feats row
    int swz = (l & 7) << 4;
    char* rowp = Sm + r * 2064;
    *(uint4*)(rowp + (off ^ swz)) = o0;
    *(uint4*)(rowp + ((off + 16) ^ swz)) = o1;
  }
  __syncthreads();
  // ---- MFMA phase: y[8,128] = S[8,1024] @ Wn (rows 8..15 duplicated) ----
  f32x4 acc2[2];
#pragma unroll
  for (int t = 0; t < 2; ++t) {
    acc2[t][0] = 0.f; acc2[t][1] = 0.f; acc2[t][2] = 0.f; acc2[t][3] = 0.f;
  }
  const char* arow = Sm + (lane & 7) * 2064;
#pragma unroll 8
  for (int kt = 0; kt < 32; ++kt) {
    int aoff = kt * 64 + g * 16;
    int key = ((aoff >> 7) & 7) << 4;
    f16x8 a = *(const f16x8*)(arow + (aoff ^ key));
    f16x8 bA = *(const f16x8*)(WnP + ((size_t)((wid * 2 + 0) * 32 + kt) * 64 + lane) * 8);
    f16x8 bB = *(const f16x8*)(WnP + ((size_t)((wid * 2 + 1) * 32 + kt) * 64 + lane) * 8);
    acc2[0] = __builtin_amdgcn_mfma_f32_16x16x32_f16(a, bA, acc2[0], 0, 0, 0);
    acc2[1] = __builtin_amdgcn_mfma_f32_16x16x32_f16(a, bB, acc2[1], 0, 0, 0);
  }
  int col0 = lane & 15;
  int rloc = (lane >> 4) * 4;
#pragma unroll
  for (int t = 0; t < 2; ++t) {
    int c = (wid * 2 + t) * 16 + col0;
    float bb = bn[c];
#pragma unroll
    for (int rr = 0; rr < 4; ++rr) {
      int r = rloc + rr;
      int row = nblk + r;
      if (r < 8 && row < N) y[(size_t)row * DOUT + c] = fmaxf(acc2[t][rr] + bb, 0.f);
    }
  }
}

extern "C" void kernel_launch(void* const* d_in, const int* in_sizes, int n_in,
                              void* d_out, int out_size, void* d_ws, size_t ws_size,
                              hipStream_t stream) {
  const float* x  = (const float*)d_in[0];
  const int*   ei = (const int*)d_in[1];
  const float* ea = (const float*)d_in[2];
  const float* Wg = (const float*)d_in[3];
  const float* bg = (const float*)d_in[4];
  const float* We = (const float*)d_in[5];
  const float* be = (const float*)d_in[6];
  const float* Wn = (const float*)d_in[7];
  const float* bn = (const float*)d_in[8];
  float* outp = (float*)d_out;
  int N = in_sizes[0] / DN;  // 50000
  int E = in_sizes[1] / 2;   // 800000

  char* p = (char*)d_ws;
  auto carve = [&](size_t bytes) {
    char* r = p;
    p += (bytes + 255) & ~(size_t)255;
    return (void*)r;
  };
  u16*   wh    = (u16*)carve((size_t)E * LE * 2);    // CSR-ordered latent weights, fp16
  u16*   wsc   = (u16*)carve((size_t)E * LE * 2);    // pre-normalized weights, fp16
  u16*   xwh   = (u16*)carve((size_t)N * LN * 2);    // xW in fp16
  float* dinv  = (float*)carve((size_t)N * LE * 4);
  u16*   WnP   = (u16*)carve((size_t)(LE * LN) * DOUT * 2);
  u16*   WgP   = (u16*)carve((size_t)DN * LN * 2);
  int*   offs  = (int*)carve((size_t)(N + 1) * 4);
  int*   cnt   = (int*)carve((size_t)N * 4);
  int*   cur   = (int*)carve((size_t)N * 4);
  int*   src   = (int*)carve((size_t)E * 4);
  int*   epos  = (int*)carve((size_t)E * 4);

  hipMemsetAsync(cnt, 0, (size_t)N * 4, stream);
  hipMemsetAsync(cur, 0, (size_t)N * 4, stream);

  // CSR build
  k_count<<<(E + 255) / 256, 256, 0, stream>>>(ei, cnt, E);
  k_scan<<<1, 1024, 0, stream>>>(cnt, offs, N);
  k_fill<<<(E + 255) / 256, 256, 0, stream>>>(ei, cur, offs, epos, src, E);
  // edge MLP directly into CSR order (fp16)
  k_edge_props<<<(E + 255) / 256, 256, 0, stream>>>(ea, We, be, epos, wh, E);
  // node GEMM path (independent of edges): xW in fp16
  k_packb<<<(((DN / 32) * (LN / 16) * 64) + 255) / 256, 256, 0, stream>>>(Wg, WgP, DN, LN);
  k_packb<<<((((LE * LN) / 32) * (DOUT / 16) * 64) + 255) / 256, 256, 0, stream>>>(Wn, WnP, LE * LN, DOUT);
  k_gemm<DN, LN, false, true, true><<<(N + 127) / 128, 256, 0, stream>>>(x, WgP, nullptr, xwh, N);
  // weighted in-degree normalization, then pre-fold dinv[src] into weights
  k_dinv<<<(N + 15) / 16, 256, 0, stream>>>(wh, offs, dinv, N);
  k_wsc<<<(E + 255) / 256, 256, 0, stream>>>(wh, src, dinv, wsc, E);
  // fused aggregation + output MLP
  k_fused<<<(N + 7) / 8, 256, 0, stream>>>(src, wsc, dinv, xwh, bg, offs, WnP, bn, outp, N);
}

// Round 7
// 422.869 us; speedup vs baseline: 1.1869x; 1.0252x over previous
//
#include <hip/hip_runtime.h>
#include <hip/hip_fp16.h>

typedef _Float16 f16x8 __attribute__((ext_vector_type(8)));
typedef float f32x4 __attribute__((ext_vector_type(4)));
typedef unsigned short u16;

#define DN 128   // node in props
#define DE 32    // edge in props
#define LE 16    // latent edges (channels)
#define LN 64    // latent nodes
#define DOUT 128 // out props

__device__ inline u16 f2h(float f) { return __half_as_ushort(__float2half(f)); }
__device__ inline float h2f(u16 u) { return __half2float(__ushort_as_half(u)); }
__device__ inline unsigned pack2h(float lo, float hi) {
  return (unsigned)f2h(lo) | ((unsigned)f2h(hi) << 16);
}
__device__ inline void unp2(unsigned u, float& a, float& b) {
  __half2 p = *reinterpret_cast<__half2*>(&u);
  a = __half2float(__low2half(p));
  b = __half2float(__high2half(p));
}
// 8 fp16 packed in uint4 -> acc[0..7] += cf * val   (targets v_fma_mix)
__device__ inline void fma8h(float cf, uint4 h, float* acc) {
  float a, b;
  unp2(h.x, a, b); acc[0] = fmaf(cf, a, acc[0]); acc[1] = fmaf(cf, b, acc[1]);
  unp2(h.y, a, b); acc[2] = fmaf(cf, a, acc[2]); acc[3] = fmaf(cf, b, acc[3]);
  unp2(h.z, a, b); acc[4] = fmaf(cf, a, acc[4]); acc[5] = fmaf(cf, b, acc[5]);
  unp2(h.w, a, b); acc[6] = fmaf(cf, a, acc[6]); acc[7] = fmaf(cf, b, acc[7]);
}

// wh[epos[e], l] = fp16(relu(edge_attr[e,:] @ W_edge + b_edge)[l])  (CSR-ordered)
__global__ __launch_bounds__(256) void k_edge_props(const float* __restrict__ ea,
    const float* __restrict__ We, const float* __restrict__ be,
    const int* __restrict__ epos, u16* __restrict__ wh, int E) {
  int e = blockIdx.x * 256 + threadIdx.x;
  if (e >= E) return;
  const float4* a4 = (const float4*)(ea + (size_t)e * DE);
  float a[DE];
#pragma unroll
  for (int j = 0; j < DE / 4; ++j) {
    float4 v = a4[j];
    a[4*j] = v.x; a[4*j+1] = v.y; a[4*j+2] = v.z; a[4*j+3] = v.w;
  }
  float acc[LE];
#pragma unroll
  for (int l = 0; l < LE; ++l) acc[l] = be[l];
#pragma unroll
  for (int k = 0; k < DE; ++k) {
    float av = a[k];
#pragma unroll
    for (int l = 0; l < LE; ++l) acc[l] = fmaf(av, We[k * LE + l], acc[l]);
  }
  uint4 o0, o1;
  o0.x = pack2h(fmaxf(acc[0], 0.f), fmaxf(acc[1], 0.f));
  o0.y = pack2h(fmaxf(acc[2], 0.f), fmaxf(acc[3], 0.f));
  o0.z = pack2h(fmaxf(acc[4], 0.f), fmaxf(acc[5], 0.f));
  o0.w = pack2h(fmaxf(acc[6], 0.f), fmaxf(acc[7], 0.f));
  o1.x = pack2h(fmaxf(acc[8], 0.f), fmaxf(acc[9], 0.f));
  o1.y = pack2h(fmaxf(acc[10], 0.f), fmaxf(acc[11], 0.f));
  o1.z = pack2h(fmaxf(acc[12], 0.f), fmaxf(acc[13], 0.f));
  o1.w = pack2h(fmaxf(acc[14], 0.f), fmaxf(acc[15], 0.f));
  uint4* o4 = (uint4*)(wh + (size_t)epos[e] * LE);
  o4[0] = o0; o4[1] = o1;
}

// Pack fp32 W[K,NCOL] into fp16 MFMA-B fragments:
// dst[((nt*KT+kt)*64+lane)*8+i] = W[kt*32+(lane>>4)*8+i][nt*16+(lane&15)]
__global__ __launch_bounds__(256) void k_packb(const float* __restrict__ W,
                                               u16* __restrict__ Bp, int K, int NCOL) {
  int NT = NCOL >> 4, KT = K >> 5;
  int total = NT * KT * 64;
  int idx = blockIdx.x * 256 + threadIdx.x;
  if (idx >= total) return;
  int lane = idx & 63;
  int rest = idx >> 6;
  int kt = rest % KT, nt = rest / KT;
  int col = nt * 16 + (lane & 15);
  int kb = kt * 32 + (lane >> 4) * 8;
  u16* dst = Bp + (size_t)idx * 8;
#pragma unroll
  for (int i = 0; i < 8; ++i) dst[i] = f2h(W[(size_t)(kb + i) * NCOL + col]);
}

__global__ __launch_bounds__(256) void k_count(const int* __restrict__ ei,
                                               int* __restrict__ cnt, int E) {
  int e = blockIdx.x * 256 + threadIdx.x;
  if (e < E) atomicAdd(&cnt[ei[E + e]], 1);
}

// single-block exclusive scan over cnt[0..N) -> offs[0..N]
__global__ __launch_bounds__(1024) void k_scan(const int* __restrict__ cnt,
                                               int* __restrict__ offs, int N) {
  __shared__ int wsum[16];
  int t = threadIdx.x;
  int chunk = (N + 1023) >> 10;
  int s0 = t * chunk;
  int s1 = min(s0 + chunk, N);
  int s = 0;
  for (int i = s0; i < s1; ++i) s += cnt[i];
  int lane = t & 63, wid = t >> 6;
  int v = s;
#pragma unroll
  for (int d = 1; d < 64; d <<= 1) {
    int u = __shfl_up(v, d);
    if (lane >= d) v += u;
  }
  if (lane == 63) wsum[wid] = v;
  __syncthreads();
  if (t == 0) {
    int run = 0;
    for (int w = 0; w < 16; ++w) { int xv = wsum[w]; wsum[w] = run; run += xv; }
  }
  __syncthreads();
  int run = v - s + wsum[wid];  // exclusive prefix for this thread
  for (int i = s0; i < s1; ++i) { offs[i] = run; run += cnt[i]; }
  if (s1 == N && s0 < N) offs[N] = run;
}

// epos[e] = CSR slot of edge e; src[slot] = source node of that edge
__global__ __launch_bounds__(256) void k_fill(const int* __restrict__ ei,
    int* __restrict__ cur, const int* __restrict__ offs,
    int* __restrict__ epos, int* __restrict__ src, int E) {
  int e = blockIdx.x * 256 + threadIdx.x;
  if (e >= E) return;
  int c = ei[E + e];
  int p = atomicAdd(&cur[c], 1);
  int pos = offs[c] + p;
  epos[e] = pos;
  src[pos] = ei[e];
}

// dinv[n,l] = rsqrt(1 + sum over CSR segment of wh[i,l])
__global__ __launch_bounds__(256) void k_dinv(const u16* __restrict__ wh,
    const int* __restrict__ offs, float* __restrict__ dinv, int N) {
  int t = threadIdx.x;
  int n = blockIdx.x * 16 + (t >> 4);
  int l = t & 15;
  if (n >= N) return;
  int i0 = offs[n], i1 = offs[n + 1];
  float s = 1.0f;  // self loop weight
  for (int i = i0; i < i1; ++i) s += h2f(wh[(size_t)i * LE + l]);
  dinv[(size_t)n * LE + l] = rsqrtf(s);
}

// pre-fold source normalization: wsc[pos,l] = fp16(wh[pos,l] * dinv[src[pos],l])
__global__ __launch_bounds__(256) void k_wsc(const u16* __restrict__ wh,
    const int* __restrict__ src, const float* __restrict__ dinv,
    u16* __restrict__ wsc, int T) {
  int pos = blockIdx.x * 256 + threadIdx.x;
  if (pos >= T) return;
  int s = src[pos];
  const uint4* w4 = (const uint4*)(wh + (size_t)pos * LE);
  const float4* d4 = (const float4*)(dinv + (size_t)s * LE);
  uint4 wa = w4[0], wb2 = w4[1];
  float4 d0 = d4[0], d1 = d4[1], d2 = d4[2], d3 = d4[3];
  float a, b;
  uint4 o0, o1;
  unp2(wa.x, a, b);  o0.x = pack2h(a * d0.x, b * d0.y);
  unp2(wa.y, a, b);  o0.y = pack2h(a * d0.z, b * d0.w);
  unp2(wa.z, a, b);  o0.z = pack2h(a * d1.x, b * d1.y);
  unp2(wa.w, a, b);  o0.w = pack2h(a * d1.z, b * d1.w);
  unp2(wb2.x, a, b); o1.x = pack2h(a * d2.x, b * d2.y);
  unp2(wb2.y, a, b); o1.y = pack2h(a * d2.z, b * d2.w);
  unp2(wb2.z, a, b); o1.z = pack2h(a * d3.x, b * d3.y);
  unp2(wb2.w, a, b); o1.w = pack2h(a * d3.z, b * d3.w);
  uint4* o4 = (uint4*)(wsc + (size_t)pos * LE);
  o4[0] = o0; o4[1] = o1;
}

// GCN aggregation, 2 waves per node (each wave owns 32 of 64 cols; 8 cols/lane).
// block = 4 waves = 2 nodes; grid = ceil(N/2). No LDS, no barrier.
// feats[n, l*64+col] = fp16( bg[col] + dn*(sum_i wsc[i,l]*xwh[src_i,col]) + dn^2*xwh[n,col] )
__global__ __launch_bounds__(256) void k_feats4(const int* __restrict__ src,
    const u16* __restrict__ wsc, const float* __restrict__ dinv,
    const u16* __restrict__ xwh, const float* __restrict__ bgcn,
    const int* __restrict__ offs, u16* __restrict__ feats, int N) {
  int wid = threadIdx.x >> 6;
  int n = blockIdx.x * 2 + (wid >> 1);
  if (n >= N) return;
  int h = wid & 1;
  int lane = threadIdx.x & 63;
  int l = lane & 15, s4 = lane >> 4;
  int colb = h * 32 + s4 * 8;   // 8 consecutive cols per lane
  const u16* xb = xwh + colb;
  float acc[8];
#pragma unroll
  for (int j = 0; j < 8; ++j) acc[j] = 0.f;
  int i0 = offs[n], i1 = offs[n + 1];
  int sA = (i0 < i1) ? src[i0] : 0;
  for (int i = i0; i < i1; i += 2) {
    bool two = (i + 1 < i1);
    int s0 = sA;
    int s1 = two ? src[i + 1] : s0;
    u16 c0h = wsc[(size_t)i * LE + l];
    u16 c1h = two ? wsc[(size_t)(i + 1) * LE + l] : (u16)0;
    uint4 r0 = *(const uint4*)(xb + (size_t)s0 * LN);
    uint4 r1 = *(const uint4*)(xb + (size_t)s1 * LN);
    if (i + 2 < i1) sA = src[i + 2];
    fma8h(h2f(c0h), r0, acc);
    fma8h(h2f(c1h), r1, acc);
  }
  float dn = dinv[(size_t)n * LE + l];
  float dn2 = dn * dn;
  uint4 xs = *(const uint4*)(xwh + (size_t)n * LN + colb);
  const float4* bgp = (const float4*)(bgcn + colb);
  float4 b0 = bgp[0], b1 = bgp[1];
  float xv[8];
  unp2(xs.x, xv[0], xv[1]); unp2(xs.y, xv[2], xv[3]);
  unp2(xs.z, xv[4], xv[5]); unp2(xs.w, xv[6], xv[7]);
  float bgv[8] = {b0.x, b0.y, b0.z, b0.w, b1.x, b1.y, b1.z, b1.w};
  float ov[8];
#pragma unroll
  for (int j = 0; j < 8; ++j) ov[j] = bgv[j] + dn * acc[j] + dn2 * xv[j];
  uint4 o;
  o.x = pack2h(ov[0], ov[1]); o.y = pack2h(ov[2], ov[3]);
  o.z = pack2h(ov[4], ov[5]); o.w = pack2h(ov[6], ov[7]);
  *(uint4*)(feats + (size_t)n * (LE * LN) + l * LN + colb) = o;
}

// C[M,NCOL] = A[M,K] @ Bpacked(fp16) (+bias, relu if FIN)
// A fp32 converted in-register (AF32) or fp16; out fp32 or fp16 (OUT16)
template <int K, int NCOL, bool FIN, bool AF32, bool OUT16>
__global__ __launch_bounds__(256) void k_gemm(const void* __restrict__ Av,
    const u16* __restrict__ Bp, const float* __restrict__ bias,
    void* __restrict__ outv, int M) {
  constexpr int NT = NCOL / 16;
  constexpr int KT = K / 32;
  const u16* A16 = (const u16*)Av;
  const float* A32 = (const float*)Av;
  int lane = threadIdx.x & 63;
  int wid = threadIdx.x >> 6;
  int m0 = blockIdx.x * 128 + wid * 32;
  f32x4 acc[2][NT];
#pragma unroll
  for (int mt = 0; mt < 2; ++mt)
#pragma unroll
    for (int nt = 0; nt < NT; ++nt) {
      acc[mt][nt][0] = 0.f; acc[mt][nt][1] = 0.f;
      acc[mt][nt][2] = 0.f; acc[mt][nt][3] = 0.f;
    }
  int r0 = m0 + (lane & 15);
  int r1 = r0 + 16;
  bool v0 = r0 < M, v1 = r1 < M;
  int ko = (lane >> 4) * 8;
#pragma unroll 4
  for (int kt = 0; kt < KT; ++kt) {
    f16x8 a0, a1;
#pragma unroll
    for (int i = 0; i < 8; ++i) { a0[i] = (_Float16)0.f; a1[i] = (_Float16)0.f; }
    if constexpr (AF32) {
      if (v0) {
        const float4* p4 = (const float4*)(A32 + (size_t)r0 * K + ko + kt * 32);
        float4 u0 = p4[0], u1 = p4[1];
        a0[0]=(_Float16)u0.x; a0[1]=(_Float16)u0.y; a0[2]=(_Float16)u0.z; a0[3]=(_Float16)u0.w;
        a0[4]=(_Float16)u1.x; a0[5]=(_Float16)u1.y; a0[6]=(_Float16)u1.z; a0[7]=(_Float16)u1.w;
      }
      if (v1) {
        const float4* p4 = (const float4*)(A32 + (size_t)r1 * K + ko + kt * 32);
        float4 u0 = p4[0], u1 = p4[1];
        a1[0]=(_Float16)u0.x; a1[1]=(_Float16)u0.y; a1[2]=(_Float16)u0.z; a1[3]=(_Float16)u0.w;
        a1[4]=(_Float16)u1.x; a1[5]=(_Float16)u1.y; a1[6]=(_Float16)u1.z; a1[7]=(_Float16)u1.w;
      }
    } else {
      if (v0) a0 = *(const f16x8*)(A16 + (size_t)r0 * K + ko + kt * 32);
      if (v1) a1 = *(const f16x8*)(A16 + (size_t)r1 * K + ko + kt * 32);
    }
#pragma unroll
    for (int nt = 0; nt < NT; ++nt) {
      f16x8 b = *(const f16x8*)(Bp + ((size_t)(nt * KT + kt) * 64 + lane) * 8);
      acc[0][nt] = __builtin_amdgcn_mfma_f32_16x16x32_f16(a0, b, acc[0][nt], 0, 0, 0);
      acc[1][nt] = __builtin_amdgcn_mfma_f32_16x16x32_f16(a1, b, acc[1][nt], 0, 0, 0);
    }
  }
  int col0 = lane & 15;
#pragma unroll
  for (int mt = 0; mt < 2; ++mt) {
    int rb = m0 + mt * 16 + ((lane >> 4) << 2);
#pragma unroll
    for (int nt = 0; nt < NT; ++nt) {
      int c = nt * 16 + col0;
      float bb = FIN ? bias[c] : 0.f;
#pragma unroll
      for (int r = 0; r < 4; ++r) {
        int row = rb + r;
        if (row < M) {
          float vv = acc[mt][nt][r] + bb;
          if (FIN) vv = fmaxf(vv, 0.f);
          if constexpr (OUT16) ((u16*)outv)[(size_t)row * NCOL + c] = f2h(vv);
          else ((float*)outv)[(size_t)row * NCOL + c] = vv;
        }
      }
    }
  }
}

extern "C" void kernel_launch(void* const* d_in, const int* in_sizes, int n_in,
                              void* d_out, int out_size, void* d_ws, size_t ws_size,
                              hipStream_t stream) {
  const float* x  = (const float*)d_in[0];
  const int*   ei = (const int*)d_in[1];
  const float* ea = (const float*)d_in[2];
  const float* Wg = (const float*)d_in[3];
  const float* bg = (const float*)d_in[4];
  const float* We = (const float*)d_in[5];
  const float* be = (const float*)d_in[6];
  const float* Wn = (const float*)d_in[7];
  const float* bn = (const float*)d_in[8];
  float* outp = (float*)d_out;
  int N = in_sizes[0] / DN;  // 50000
  int E = in_sizes[1] / 2;   // 800000

  char* p = (char*)d_ws;
  auto carve = [&](size_t bytes) {
    char* r = p;
    p += (bytes + 255) & ~(size_t)255;
    return (void*)r;
  };
  u16*   wh    = (u16*)carve((size_t)E * LE * 2);    // CSR-ordered latent weights, fp16
  u16*   wsc   = (u16*)carve((size_t)E * LE * 2);    // pre-normalized weights, fp16
  u16*   xwh   = (u16*)carve((size_t)N * LN * 2);    // xW in fp16
  u16*   feats = (u16*)carve((size_t)N * (LE * LN) * 2);  // aggregated feats fp16
  float* dinv  = (float*)carve((size_t)N * LE * 4);
  u16*   WnP   = (u16*)carve((size_t)(LE * LN) * DOUT * 2);
  u16*   WgP   = (u16*)carve((size_t)DN * LN * 2);
  int*   offs  = (int*)carve((size_t)(N + 1) * 4);
  int*   cnt   = (int*)carve((size_t)N * 4);
  int*   cur   = (int*)carve((size_t)N * 4);
  int*   src   = (int*)carve((size_t)E * 4);
  int*   epos  = (int*)carve((size_t)E * 4);

  hipMemsetAsync(cnt, 0, (size_t)N * 4, stream);
  hipMemsetAsync(cur, 0, (size_t)N * 4, stream);

  // CSR build
  k_count<<<(E + 255) / 256, 256, 0, stream>>>(ei, cnt, E);
  k_scan<<<1, 1024, 0, stream>>>(cnt, offs, N);
  k_fill<<<(E + 255) / 256, 256, 0, stream>>>(ei, cur, offs, epos, src, E);
  // edge MLP directly into CSR order (fp16)
  k_edge_props<<<(E + 255) / 256, 256, 0, stream>>>(ea, We, be, epos, wh, E);
  // node GEMM path (independent of edges): xW in fp16
  k_packb<<<(((DN / 32) * (LN / 16) * 64) + 255) / 256, 256, 0, stream>>>(Wg, WgP, DN, LN);
  k_packb<<<((((LE * LN) / 32) * (DOUT / 16) * 64) + 255) / 256, 256, 0, stream>>>(Wn, WnP, LE * LN, DOUT);
  k_gemm<DN, LN, false, true, true><<<(N + 127) / 128, 256, 0, stream>>>(x, WgP, nullptr, xwh, N);
  // weighted in-degree normalization, then pre-fold dinv[src] into weights
  k_dinv<<<(N + 15) / 16, 256, 0, stream>>>(wh, offs, dinv, N);
  k_wsc<<<(E + 255) / 256, 256, 0, stream>>>(wh, src, dinv, wsc, E);
  // aggregation: 2 waves per node, 8 cols per lane
  k_feats4<<<(N + 1) / 2, 256, 0, stream>>>(src, wsc, dinv, xwh, bg, offs, feats, N);
  // output MLP (MFMA, 128-row blocks)
  k_gemm<LE * LN, DOUT, true, false, false><<<(N + 127) / 128, 256, 0, stream>>>(feats, WnP, bn, outp, N);
}

// Round 8
// 420.616 us; speedup vs baseline: 1.1932x; 1.0054x over previous
//
#include <hip/hip_runtime.h>
#include <hip/hip_fp16.h>

typedef _Float16 f16x8 __attribute__((ext_vector_type(8)));
typedef float f32x4 __attribute__((ext_vector_type(4)));
typedef unsigned short u16;

#define DN 128   // node in props
#define DE 32    // edge in props
#define LE 16    // latent edges (channels)
#define LN 64    // latent nodes
#define DOUT 128 // out props

__device__ inline u16 f2h(float f) { return __half_as_ushort(__float2half(f)); }
__device__ inline float h2f(u16 u) { return __half2float(__ushort_as_half(u)); }
__device__ inline unsigned pack2h(float lo, float hi) {
  return (unsigned)f2h(lo) | ((unsigned)f2h(hi) << 16);
}
__device__ inline void unp2(unsigned u, float& a, float& b) {
  __half2 p = *reinterpret_cast<__half2*>(&u);
  a = __half2float(__low2half(p));
  b = __half2float(__high2half(p));
}
__device__ inline __half2 u2h2(unsigned u) {
  return *reinterpret_cast<__half2*>(&u);
}
__device__ inline unsigned h22u(__half2 h) {
  return *reinterpret_cast<unsigned*>(&h);
}

// CSR-ordered edge MLP: pos -> e = eperm[pos]; gather ea row; coalesced wh write
// wh[pos, l] = fp16(relu(edge_attr[e,:] @ W_edge + b_edge)[l])
__global__ __launch_bounds__(256) void k_edge_props(const float* __restrict__ ea,
    const float* __restrict__ We, const float* __restrict__ be,
    const int* __restrict__ eperm, u16* __restrict__ wh, int E) {
  int pos = blockIdx.x * 256 + threadIdx.x;
  if (pos >= E) return;
  int e = eperm[pos];
  const float4* a4 = (const float4*)(ea + (size_t)e * DE);
  float a[DE];
#pragma unroll
  for (int j = 0; j < DE / 4; ++j) {
    float4 v = a4[j];
    a[4*j] = v.x; a[4*j+1] = v.y; a[4*j+2] = v.z; a[4*j+3] = v.w;
  }
  float acc[LE];
#pragma unroll
  for (int l = 0; l < LE; ++l) acc[l] = be[l];
#pragma unroll
  for (int k = 0; k < DE; ++k) {
    float av = a[k];
#pragma unroll
    for (int l = 0; l < LE; ++l) acc[l] = fmaf(av, We[k * LE + l], acc[l]);
  }
  uint4 o0, o1;
  o0.x = pack2h(fmaxf(acc[0], 0.f), fmaxf(acc[1], 0.f));
  o0.y = pack2h(fmaxf(acc[2], 0.f), fmaxf(acc[3], 0.f));
  o0.z = pack2h(fmaxf(acc[4], 0.f), fmaxf(acc[5], 0.f));
  o0.w = pack2h(fmaxf(acc[6], 0.f), fmaxf(acc[7], 0.f));
  o1.x = pack2h(fmaxf(acc[8], 0.f), fmaxf(acc[9], 0.f));
  o1.y = pack2h(fmaxf(acc[10], 0.f), fmaxf(acc[11], 0.f));
  o1.z = pack2h(fmaxf(acc[12], 0.f), fmaxf(acc[13], 0.f));
  o1.w = pack2h(fmaxf(acc[14], 0.f), fmaxf(acc[15], 0.f));
  uint4* o4 = (uint4*)(wh + (size_t)pos * LE);
  o4[0] = o0; o4[1] = o1;
}

// Pack fp32 W[K,NCOL] into fp16 MFMA-B fragments (both weight mats, one launch)
// dst[((nt*KT+kt)*64+lane)*8+i] = W[kt*32+(lane>>4)*8+i][nt*16+(lane&15)]
__device__ inline void packb_one(const float* __restrict__ W, u16* __restrict__ Bp,
                                 int idx, int K, int NCOL) {
  int KT = K >> 5;
  int lane = idx & 63;
  int rest = idx >> 6;
  int kt = rest % KT, nt = rest / KT;
  int col = nt * 16 + (lane & 15);
  int kb = kt * 32 + (lane >> 4) * 8;
  u16* dst = Bp + (size_t)idx * 8;
#pragma unroll
  for (int i = 0; i < 8; ++i) dst[i] = f2h(W[(size_t)(kb + i) * NCOL + col]);
}
__global__ __launch_bounds__(256) void k_packb2(const float* __restrict__ Wg,
    u16* __restrict__ WgP, const float* __restrict__ Wn, u16* __restrict__ WnP) {
  const int totA = (DN / 32) * (LN / 16) * 64;          // 1024
  const int totB = ((LE * LN) / 32) * (DOUT / 16) * 64; // 16384
  int idx = blockIdx.x * 256 + threadIdx.x;
  if (idx < totA) packb_one(Wg, WgP, idx, DN, LN);
  else if (idx < totA + totB) packb_one(Wn, WnP, idx - totA, LE * LN, DOUT);
}

__global__ __launch_bounds__(256) void k_count(const int* __restrict__ ei,
                                               int* __restrict__ cnt, int E) {
  int e = blockIdx.x * 256 + threadIdx.x;
  if (e < E) atomicAdd(&cnt[ei[E + e]], 1);
}

// single-block exclusive scan over cnt[0..N) -> offs[0..N]
__global__ __launch_bounds__(1024) void k_scan(const int* __restrict__ cnt,
                                               int* __restrict__ offs, int N) {
  __shared__ int wsum[16];
  int t = threadIdx.x;
  int chunk = (N + 1023) >> 10;
  int s0 = t * chunk;
  int s1 = min(s0 + chunk, N);
  int s = 0;
  for (int i = s0; i < s1; ++i) s += cnt[i];
  int lane = t & 63, wid = t >> 6;
  int v = s;
#pragma unroll
  for (int d = 1; d < 64; d <<= 1) {
    int u = __shfl_up(v, d);
    if (lane >= d) v += u;
  }
  if (lane == 63) wsum[wid] = v;
  __syncthreads();
  if (t == 0) {
    int run = 0;
    for (int w = 0; w < 16; ++w) { int xv = wsum[w]; wsum[w] = run; run += xv; }
  }
  __syncthreads();
  int run = v - s + wsum[wid];  // exclusive prefix for this thread
  for (int i = s0; i < s1; ++i) { offs[i] = run; run += cnt[i]; }
  if (s1 == N && s0 < N) offs[N] = run;
}

// eperm[pos] = edge id at CSR slot pos; src[pos] = source node
__global__ __launch_bounds__(256) void k_fill(const int* __restrict__ ei,
    int* __restrict__ cur, const int* __restrict__ offs,
    int* __restrict__ eperm, int* __restrict__ src, int E) {
  int e = blockIdx.x * 256 + threadIdx.x;
  if (e >= E) return;
  int c = ei[E + e];
  int p = atomicAdd(&cur[c], 1);
  int pos = offs[c] + p;
  eperm[pos] = e;
  src[pos] = ei[e];
}

// dinvh[n,l] = fp16(rsqrt(1 + sum over CSR segment of wh[i,l]))
__global__ __launch_bounds__(256) void k_dinv(const u16* __restrict__ wh,
    const int* __restrict__ offs, u16* __restrict__ dinvh, int N) {
  int t = threadIdx.x;
  int n = blockIdx.x * 16 + (t >> 4);
  int l = t & 15;
  if (n >= N) return;
  int i0 = offs[n], i1 = offs[n + 1];
  float s = 1.0f;  // self loop weight
  for (int i = i0; i < i1; ++i) s += h2f(wh[(size_t)i * LE + l]);
  dinvh[(size_t)n * LE + l] = f2h(rsqrtf(s));
}

// pre-fold source normalization (packed fp16): wsc[pos,l] = wh[pos,l]*dinvh[src,l]
__global__ __launch_bounds__(256) void k_wsc(const u16* __restrict__ wh,
    const int* __restrict__ src, const u16* __restrict__ dinvh,
    u16* __restrict__ wsc, int T) {
  int pos = blockIdx.x * 256 + threadIdx.x;
  if (pos >= T) return;
  int s = src[pos];
  const uint4* w4 = (const uint4*)(wh + (size_t)pos * LE);
  const uint4* d4 = (const uint4*)(dinvh + (size_t)s * LE);
  uint4 wa = w4[0], wb = w4[1];
  uint4 da = d4[0], db = d4[1];
  uint4 o0, o1;
  o0.x = h22u(__hmul2(u2h2(wa.x), u2h2(da.x)));
  o0.y = h22u(__hmul2(u2h2(wa.y), u2h2(da.y)));
  o0.z = h22u(__hmul2(u2h2(wa.z), u2h2(da.z)));
  o0.w = h22u(__hmul2(u2h2(wa.w), u2h2(da.w)));
  o1.x = h22u(__hmul2(u2h2(wb.x), u2h2(db.x)));
  o1.y = h22u(__hmul2(u2h2(wb.y), u2h2(db.y)));
  o1.z = h22u(__hmul2(u2h2(wb.z), u2h2(db.z)));
  o1.w = h22u(__hmul2(u2h2(wb.w), u2h2(db.w)));
  uint4* o4 = (uint4*)(wsc + (size_t)pos * LE);
  o4[0] = o0; o4[1] = o1;
}

// GCN aggregation, 2 waves per node, packed-fp16 FMA (v_pk_fma_f16), fp16 acc.
// lane: l = lane&15 (channel), s4 = lane>>4; 8 cols/lane.
// feats[n, l*64+col] = fp16( bg[col] + dn*(sum_i wsc[i,l]*xwh[src_i,col]) + dn^2*xwh[n,col] )
__global__ __launch_bounds__(256) void k_feats5(const int* __restrict__ src,
    const u16* __restrict__ wsc, const u16* __restrict__ dinvh,
    const u16* __restrict__ xwh, const float* __restrict__ bgcn,
    const int* __restrict__ offs, u16* __restrict__ feats, int N) {
  int wid = threadIdx.x >> 6;
  int n = blockIdx.x * 2 + (wid >> 1);
  if (n >= N) return;
  int h = wid & 1;
  int lane = threadIdx.x & 63;
  int l = lane & 15, s4 = lane >> 4;
  int colb = h * 32 + s4 * 8;   // 8 consecutive cols per lane
  const u16* xb = xwh + colb;
  __half2 acc0, acc1, acc2, acc3;
  acc0 = acc1 = acc2 = acc3 = u2h2(0u);
  int i0 = offs[n], i1 = offs[n + 1];
  int sA = (i0 < i1) ? src[i0] : 0;
  for (int i = i0; i < i1; i += 2) {
    bool two = (i + 1 < i1);
    int s0 = sA;
    int s1 = two ? src[i + 1] : s0;
    unsigned c0 = wsc[(size_t)i * LE + l];
    unsigned c1 = two ? wsc[(size_t)(i + 1) * LE + l] : 0u;
    uint4 r0 = *(const uint4*)(xb + (size_t)s0 * LN);
    uint4 r1 = *(const uint4*)(xb + (size_t)s1 * LN);
    if (i + 2 < i1) sA = src[i + 2];
    __half2 c02 = u2h2(c0 | (c0 << 16));
    __half2 c12 = u2h2(c1 | (c1 << 16));
    acc0 = __hfma2(c02, u2h2(r0.x), acc0);
    acc1 = __hfma2(c02, u2h2(r0.y), acc1);
    acc2 = __hfma2(c02, u2h2(r0.z), acc2);
    acc3 = __hfma2(c02, u2h2(r0.w), acc3);
    acc0 = __hfma2(c12, u2h2(r1.x), acc0);
    acc1 = __hfma2(c12, u2h2(r1.y), acc1);
    acc2 = __hfma2(c12, u2h2(r1.z), acc2);
    acc3 = __hfma2(c12, u2h2(r1.w), acc3);
  }
  float dn = h2f(dinvh[(size_t)n * LE + l]);
  float dn2 = dn * dn;
  uint4 xs = *(const uint4*)(xwh + (size_t)n * LN + colb);
  const float4* bgp = (const float4*)(bgcn + colb);
  float4 b0 = bgp[0], b1 = bgp[1];
  float xv[8];
  unp2(xs.x, xv[0], xv[1]); unp2(xs.y, xv[2], xv[3]);
  unp2(xs.z, xv[4], xv[5]); unp2(xs.w, xv[6], xv[7]);
  float av[8];
  unp2(h22u(acc0), av[0], av[1]); unp2(h22u(acc1), av[2], av[3]);
  unp2(h22u(acc2), av[4], av[5]); unp2(h22u(acc3), av[6], av[7]);
  float bgv[8] = {b0.x, b0.y, b0.z, b0.w, b1.x, b1.y, b1.z, b1.w};
  float ov[8];
#pragma unroll
  for (int j = 0; j < 8; ++j) ov[j] = bgv[j] + dn * av[j] + dn2 * xv[j];
  uint4 o;
  o.x = pack2h(ov[0], ov[1]); o.y = pack2h(ov[2], ov[3]);
  o.z = pack2h(ov[4], ov[5]); o.w = pack2h(ov[6], ov[7]);
  *(uint4*)(feats + (size_t)n * (LE * LN) + l * LN + colb) = o;
}

// C[M,NCOL] = A[M,K] @ Bpacked(fp16) (+bias, relu if FIN)
// A fp32 converted in-register (AF32) or fp16; out fp32 or fp16 (OUT16)
template <int K, int NCOL, bool FIN, bool AF32, bool OUT16>
__global__ __launch_bounds__(256) void k_gemm(const void* __restrict__ Av,
    const u16* __restrict__ Bp, const float* __restrict__ bias,
    void* __restrict__ outv, int M) {
  constexpr int NT = NCOL / 16;
  constexpr int KT = K / 32;
  const u16* A16 = (const u16*)Av;
  const float* A32 = (const float*)Av;
  int lane = threadIdx.x & 63;
  int wid = threadIdx.x >> 6;
  int m0 = blockIdx.x * 128 + wid * 32;
  f32x4 acc[2][NT];
#pragma unroll
  for (int mt = 0; mt < 2; ++mt)
#pragma unroll
    for (int nt = 0; nt < NT; ++nt) {
      acc[mt][nt][0] = 0.f; acc[mt][nt][1] = 0.f;
      acc[mt][nt][2] = 0.f; acc[mt][nt][3] = 0.f;
    }
  int r0 = m0 + (lane & 15);
  int r1 = r0 + 16;
  bool v0 = r0 < M, v1 = r1 < M;
  int ko = (lane >> 4) * 8;
#pragma unroll 4
  for (int kt = 0; kt < KT; ++kt) {
    f16x8 a0, a1;
#pragma unroll
    for (int i = 0; i < 8; ++i) { a0[i] = (_Float16)0.f; a1[i] = (_Float16)0.f; }
    if constexpr (AF32) {
      if (v0) {
        const float4* p4 = (const float4*)(A32 + (size_t)r0 * K + ko + kt * 32);
        float4 u0 = p4[0], u1 = p4[1];
        a0[0]=(_Float16)u0.x; a0[1]=(_Float16)u0.y; a0[2]=(_Float16)u0.z; a0[3]=(_Float16)u0.w;
        a0[4]=(_Float16)u1.x; a0[5]=(_Float16)u1.y; a0[6]=(_Float16)u1.z; a0[7]=(_Float16)u1.w;
      }
      if (v1) {
        const float4* p4 = (const float4*)(A32 + (size_t)r1 * K + ko + kt * 32);
        float4 u0 = p4[0], u1 = p4[1];
        a1[0]=(_Float16)u0.x; a1[1]=(_Float16)u0.y; a1[2]=(_Float16)u0.z; a1[3]=(_Float16)u0.w;
        a1[4]=(_Float16)u1.x; a1[5]=(_Float16)u1.y; a1[6]=(_Float16)u1.z; a1[7]=(_Float16)u1.w;
      }
    } else {
      if (v0) a0 = *(const f16x8*)(A16 + (size_t)r0 * K + ko + kt * 32);
      if (v1) a1 = *(const f16x8*)(A16 + (size_t)r1 * K + ko + kt * 32);
    }
#pragma unroll
    for (int nt = 0; nt < NT; ++nt) {
      f16x8 b = *(const f16x8*)(Bp + ((size_t)(nt * KT + kt) * 64 + lane) * 8);
      acc[0][nt] = __builtin_amdgcn_mfma_f32_16x16x32_f16(a0, b, acc[0][nt], 0, 0, 0);
      acc[1][nt] = __builtin_amdgcn_mfma_f32_16x16x32_f16(a1, b, acc[1][nt], 0, 0, 0);
    }
  }
  int col0 = lane & 15;
#pragma unroll
  for (int mt = 0; mt < 2; ++mt) {
    int rb = m0 + mt * 16 + ((lane >> 4) << 2);
#pragma unroll
    for (int nt = 0; nt < NT; ++nt) {
      int c = nt * 16 + col0;
      float bb = FIN ? bias[c] : 0.f;
#pragma unroll
      for (int r = 0; r < 4; ++r) {
        int row = rb + r;
        if (row < M) {
          float vv = acc[mt][nt][r] + bb;
          if (FIN) vv = fmaxf(vv, 0.f);
          if constexpr (OUT16) ((u16*)outv)[(size_t)row * NCOL + c] = f2h(vv);
          else ((float*)outv)[(size_t)row * NCOL + c] = vv;
        }
      }
    }
  }
}

extern "C" void kernel_launch(void* const* d_in, const int* in_sizes, int n_in,
                              void* d_out, int out_size, void* d_ws, size_t ws_size,
                              hipStream_t stream) {
  const float* x  = (const float*)d_in[0];
  const int*   ei = (const int*)d_in[1];
  const float* ea = (const float*)d_in[2];
  const float* Wg = (const float*)d_in[3];
  const float* bg = (const float*)d_in[4];
  const float* We = (const float*)d_in[5];
  const float* be = (const float*)d_in[6];
  const float* Wn = (const float*)d_in[7];
  const float* bn = (const float*)d_in[8];
  float* outp = (float*)d_out;
  int N = in_sizes[0] / DN;  // 50000
  int E = in_sizes[1] / 2;   // 800000

  char* p = (char*)d_ws;
  auto carve = [&](size_t bytes) {
    char* r = p;
    p += (bytes + 255) & ~(size_t)255;
    return (void*)r;
  };
  u16*   wh    = (u16*)carve((size_t)E * LE * 2);    // CSR-ordered latent weights, fp16
  u16*   wsc   = (u16*)carve((size_t)E * LE * 2);    // pre-normalized weights, fp16
  u16*   xwh   = (u16*)carve((size_t)N * LN * 2);    // xW in fp16
  u16*   feats = (u16*)carve((size_t)N * (LE * LN) * 2);  // aggregated feats fp16
  u16*   dinvh = (u16*)carve((size_t)N * LE * 2);    // dinv fp16
  u16*   WnP   = (u16*)carve((size_t)(LE * LN) * DOUT * 2);
  u16*   WgP   = (u16*)carve((size_t)DN * LN * 2);
  int*   offs  = (int*)carve((size_t)(N + 1) * 4);
  int*   cnt   = (int*)carve((size_t)N * 4);
  int*   cur   = (int*)carve((size_t)N * 4);
  int*   src   = (int*)carve((size_t)E * 4);
  int*   eperm = (int*)carve((size_t)E * 4);

  hipMemsetAsync(cnt, 0, (size_t)N * 4, stream);
  hipMemsetAsync(cur, 0, (size_t)N * 4, stream);

  // CSR build
  k_count<<<(E + 255) / 256, 256, 0, stream>>>(ei, cnt, E);
  k_scan<<<1, 1024, 0, stream>>>(cnt, offs, N);
  k_fill<<<(E + 255) / 256, 256, 0, stream>>>(ei, cur, offs, eperm, src, E);
  // edge MLP: gather ea rows in CSR order, coalesced wh write
  k_edge_props<<<(E + 255) / 256, 256, 0, stream>>>(ea, We, be, eperm, wh, E);
  // weight packing (both mats), node GEMM path: xW in fp16
  k_packb2<<<(1024 + 16384 + 255) / 256, 256, 0, stream>>>(Wg, WgP, Wn, WnP);
  k_gemm<DN, LN, false, true, true><<<(N + 127) / 128, 256, 0, stream>>>(x, WgP, nullptr, xwh, N);
  // weighted in-degree normalization (fp16), pre-fold dinv[src] into weights
  k_dinv<<<(N + 15) / 16, 256, 0, stream>>>(wh, offs, dinvh, N);
  k_wsc<<<(E + 255) / 256, 256, 0, stream>>>(wh, src, dinvh, wsc, E);
  // aggregation: 2 waves per node, packed fp16 FMA
  k_feats5<<<(N + 1) / 2, 256, 0, stream>>>(src, wsc, dinvh, xwh, bg, offs, feats, N);
  // output MLP (MFMA, 128-row blocks)
  k_gemm<LE * LN, DOUT, true, false, false><<<(N + 127) / 128, 256, 0, stream>>>(feats, WnP, bn, outp, N);
}

// Round 9
// 397.308 us; speedup vs baseline: 1.2632x; 1.0587x over previous
//
#include <hip/hip_runtime.h>
#include <hip/hip_fp16.h>

typedef _Float16 f16x8 __attribute__((ext_vector_type(8)));
typedef float f32x4 __attribute__((ext_vector_type(4)));
typedef unsigned short u16;

#define DN 128   // node in props
#define DE 32    // edge in props
#define LE 16    // latent edges (channels)
#define LN 64    // latent nodes
#define DOUT 128 // out props

__device__ inline u16 f2h(float f) { return __half_as_ushort(__float2half(f)); }
__device__ inline float h2f(u16 u) { return __half2float(__ushort_as_half(u)); }
__device__ inline unsigned pack2h(float lo, float hi) {
  return (unsigned)f2h(lo) | ((unsigned)f2h(hi) << 16);
}
__device__ inline void unp2(unsigned u, float& a, float& b) {
  __half2 p = *reinterpret_cast<__half2*>(&u);
  a = __half2float(__low2half(p));
  b = __half2float(__high2half(p));
}
__device__ inline __half2 u2h2(unsigned u) {
  return *reinterpret_cast<__half2*>(&u);
}
__device__ inline unsigned h22u(__half2 h) {
  return *reinterpret_cast<unsigned*>(&h);
}

// CSR-ordered edge MLP: pos -> e = eperm[pos]; gather ea row; coalesced wh write
// wh[pos, l] = fp16(relu(edge_attr[e,:] @ W_edge + b_edge)[l])
__global__ __launch_bounds__(256) void k_edge_props(const float* __restrict__ ea,
    const float* __restrict__ We, const float* __restrict__ be,
    const int* __restrict__ eperm, u16* __restrict__ wh, int E) {
  int pos = blockIdx.x * 256 + threadIdx.x;
  if (pos >= E) return;
  int e = eperm[pos];
  const float4* a4 = (const float4*)(ea + (size_t)e * DE);
  float a[DE];
#pragma unroll
  for (int j = 0; j < DE / 4; ++j) {
    float4 v = a4[j];
    a[4*j] = v.x; a[4*j+1] = v.y; a[4*j+2] = v.z; a[4*j+3] = v.w;
  }
  float acc[LE];
#pragma unroll
  for (int l = 0; l < LE; ++l) acc[l] = be[l];
#pragma unroll
  for (int k = 0; k < DE; ++k) {
    float av = a[k];
#pragma unroll
    for (int l = 0; l < LE; ++l) acc[l] = fmaf(av, We[k * LE + l], acc[l]);
  }
  uint4 o0, o1;
  o0.x = pack2h(fmaxf(acc[0], 0.f), fmaxf(acc[1], 0.f));
  o0.y = pack2h(fmaxf(acc[2], 0.f), fmaxf(acc[3], 0.f));
  o0.z = pack2h(fmaxf(acc[4], 0.f), fmaxf(acc[5], 0.f));
  o0.w = pack2h(fmaxf(acc[6], 0.f), fmaxf(acc[7], 0.f));
  o1.x = pack2h(fmaxf(acc[8], 0.f), fmaxf(acc[9], 0.f));
  o1.y = pack2h(fmaxf(acc[10], 0.f), fmaxf(acc[11], 0.f));
  o1.z = pack2h(fmaxf(acc[12], 0.f), fmaxf(acc[13], 0.f));
  o1.w = pack2h(fmaxf(acc[14], 0.f), fmaxf(acc[15], 0.f));
  uint4* o4 = (uint4*)(wh + (size_t)pos * LE);
  o4[0] = o0; o4[1] = o1;
}

// Pack fp32 W[K,NCOL] into fp16 MFMA-B fragments (both weight mats, one launch)
// dst[((nt*KT+kt)*64+lane)*8+i] = W[kt*32+(lane>>4)*8+i][nt*16+(lane&15)]
__device__ inline void packb_one(const float* __restrict__ W, u16* __restrict__ Bp,
                                 int idx, int K, int NCOL) {
  int KT = K >> 5;
  int lane = idx & 63;
  int rest = idx >> 6;
  int kt = rest % KT, nt = rest / KT;
  int col = nt * 16 + (lane & 15);
  int kb = kt * 32 + (lane >> 4) * 8;
  u16* dst = Bp + (size_t)idx * 8;
#pragma unroll
  for (int i = 0; i < 8; ++i) dst[i] = f2h(W[(size_t)(kb + i) * NCOL + col]);
}
__global__ __launch_bounds__(256) void k_packb2(const float* __restrict__ Wg,
    u16* __restrict__ WgP, const float* __restrict__ Wn, u16* __restrict__ WnP) {
  const int totA = (DN / 32) * (LN / 16) * 64;          // 1024
  const int totB = ((LE * LN) / 32) * (DOUT / 16) * 64; // 16384
  int idx = blockIdx.x * 256 + threadIdx.x;
  if (idx < totA) packb_one(Wg, WgP, idx, DN, LN);
  else if (idx < totA + totB) packb_one(Wn, WnP, idx - totA, LE * LN, DOUT);
}

__global__ __launch_bounds__(256) void k_count(const int* __restrict__ ei,
                                               int* __restrict__ cnt, int E) {
  int e = blockIdx.x * 256 + threadIdx.x;
  if (e < E) atomicAdd(&cnt[ei[E + e]], 1);
}

// single-block exclusive scan over cnt[0..N) -> offs[0..N]
__global__ __launch_bounds__(1024) void k_scan(const int* __restrict__ cnt,
                                               int* __restrict__ offs, int N) {
  __shared__ int wsum[16];
  int t = threadIdx.x;
  int chunk = (N + 1023) >> 10;
  int s0 = t * chunk;
  int s1 = min(s0 + chunk, N);
  int s = 0;
  for (int i = s0; i < s1; ++i) s += cnt[i];
  int lane = t & 63, wid = t >> 6;
  int v = s;
#pragma unroll
  for (int d = 1; d < 64; d <<= 1) {
    int u = __shfl_up(v, d);
    if (lane >= d) v += u;
  }
  if (lane == 63) wsum[wid] = v;
  __syncthreads();
  if (t == 0) {
    int run = 0;
    for (int w = 0; w < 16; ++w) { int xv = wsum[w]; wsum[w] = run; run += xv; }
  }
  __syncthreads();
  int run = v - s + wsum[wid];  // exclusive prefix for this thread
  for (int i = s0; i < s1; ++i) { offs[i] = run; run += cnt[i]; }
  if (s1 == N && s0 < N) offs[N] = run;
}

// eperm[pos] = edge id at CSR slot pos; src[pos] = source node
__global__ __launch_bounds__(256) void k_fill(const int* __restrict__ ei,
    int* __restrict__ cur, const int* __restrict__ offs,
    int* __restrict__ eperm, int* __restrict__ src, int E) {
  int e = blockIdx.x * 256 + threadIdx.x;
  if (e >= E) return;
  int c = ei[E + e];
  int p = atomicAdd(&cur[c], 1);
  int pos = offs[c] + p;
  eperm[pos] = e;
  src[pos] = ei[e];
}

// dinvh[n,l] = fp16(rsqrt(1 + sum over CSR segment of wh[i,l]))
__global__ __launch_bounds__(256) void k_dinv(const u16* __restrict__ wh,
    const int* __restrict__ offs, u16* __restrict__ dinvh, int N) {
  int t = threadIdx.x;
  int n = blockIdx.x * 16 + (t >> 4);
  int l = t & 15;
  if (n >= N) return;
  int i0 = offs[n], i1 = offs[n + 1];
  float s = 1.0f;  // self loop weight
  for (int i = i0; i < i1; ++i) s += h2f(wh[(size_t)i * LE + l]);
  dinvh[(size_t)n * LE + l] = f2h(rsqrtf(s));
}

// pre-fold source normalization (packed fp16): wsc[pos,l] = wh[pos,l]*dinvh[src,l]
__global__ __launch_bounds__(256) void k_wsc(const u16* __restrict__ wh,
    const int* __restrict__ src, const u16* __restrict__ dinvh,
    u16* __restrict__ wsc, int T) {
  int pos = blockIdx.x * 256 + threadIdx.x;
  if (pos >= T) return;
  int s = src[pos];
  const uint4* w4 = (const uint4*)(wh + (size_t)pos * LE);
  const uint4* d4 = (const uint4*)(dinvh + (size_t)s * LE);
  uint4 wa = w4[0], wb = w4[1];
  uint4 da = d4[0], db = d4[1];
  uint4 o0, o1;
  o0.x = h22u(__hmul2(u2h2(wa.x), u2h2(da.x)));
  o0.y = h22u(__hmul2(u2h2(wa.y), u2h2(da.y)));
  o0.z = h22u(__hmul2(u2h2(wa.z), u2h2(da.z)));
  o0.w = h22u(__hmul2(u2h2(wa.w), u2h2(da.w)));
  o1.x = h22u(__hmul2(u2h2(wb.x), u2h2(db.x)));
  o1.y = h22u(__hmul2(u2h2(wb.y), u2h2(db.y)));
  o1.z = h22u(__hmul2(u2h2(wb.z), u2h2(db.z)));
  o1.w = h22u(__hmul2(u2h2(wb.w), u2h2(db.w)));
  uint4* o4 = (uint4*)(wsc + (size_t)pos * LE);
  o4[0] = o0; o4[1] = o1;
}

// GCN aggregation, ONE wave per node: lane l = lane&15 (channel), g = lane>>4;
// 16 cols/lane (cols g*16..g*16+15), fp16 acc (8 half2), packed fp16 FMA.
// Per edge: 1 wsc broadcast-load + 2 uint4 xwh gather + 8 hfma2.
// feats[n, l*64+col] = fp16( bg[col] + dn*(sum_i wsc[i,l]*xwh[src_i,col]) + dn^2*xwh[n,col] )
__global__ __launch_bounds__(256) void k_feats6(const int* __restrict__ src,
    const u16* __restrict__ wsc, const u16* __restrict__ dinvh,
    const u16* __restrict__ xwh, const float* __restrict__ bgcn,
    const int* __restrict__ offs, u16* __restrict__ feats, int N) {
  int wid = threadIdx.x >> 6;
  int n = blockIdx.x * 4 + wid;
  if (n >= N) return;
  int lane = threadIdx.x & 63;
  int l = lane & 15, g = lane >> 4;
  int colb = g * 16;            // 16 consecutive cols per lane
  const u16* xb = xwh + colb;
  __half2 acc[8];
#pragma unroll
  for (int j = 0; j < 8; ++j) acc[j] = u2h2(0u);
  int i0 = offs[n], i1 = offs[n + 1];
  int sA = (i0 < i1) ? src[i0] : 0;
  for (int i = i0; i < i1; i += 2) {
    bool two = (i + 1 < i1);
    int s0 = sA;
    int s1 = two ? src[i + 1] : s0;
    unsigned c0 = wsc[(size_t)i * LE + l];
    unsigned c1 = two ? wsc[(size_t)(i + 1) * LE + l] : 0u;
    const uint4* p0 = (const uint4*)(xb + (size_t)s0 * LN);
    const uint4* p1 = (const uint4*)(xb + (size_t)s1 * LN);
    uint4 r0a = p0[0], r0b = p0[1];
    uint4 r1a = p1[0], r1b = p1[1];
    if (i + 2 < i1) sA = src[i + 2];
    __half2 c02 = u2h2(c0 | (c0 << 16));
    __half2 c12 = u2h2(c1 | (c1 << 16));
    acc[0] = __hfma2(c02, u2h2(r0a.x), acc[0]);
    acc[1] = __hfma2(c02, u2h2(r0a.y), acc[1]);
    acc[2] = __hfma2(c02, u2h2(r0a.z), acc[2]);
    acc[3] = __hfma2(c02, u2h2(r0a.w), acc[3]);
    acc[4] = __hfma2(c02, u2h2(r0b.x), acc[4]);
    acc[5] = __hfma2(c02, u2h2(r0b.y), acc[5]);
    acc[6] = __hfma2(c02, u2h2(r0b.z), acc[6]);
    acc[7] = __hfma2(c02, u2h2(r0b.w), acc[7]);
    acc[0] = __hfma2(c12, u2h2(r1a.x), acc[0]);
    acc[1] = __hfma2(c12, u2h2(r1a.y), acc[1]);
    acc[2] = __hfma2(c12, u2h2(r1a.z), acc[2]);
    acc[3] = __hfma2(c12, u2h2(r1a.w), acc[3]);
    acc[4] = __hfma2(c12, u2h2(r1b.x), acc[4]);
    acc[5] = __hfma2(c12, u2h2(r1b.y), acc[5]);
    acc[6] = __hfma2(c12, u2h2(r1b.z), acc[6]);
    acc[7] = __hfma2(c12, u2h2(r1b.w), acc[7]);
  }
  float dn = h2f(dinvh[(size_t)n * LE + l]);
  float dn2 = dn * dn;
  const uint4* xs4 = (const uint4*)(xwh + (size_t)n * LN + colb);
  uint4 m0 = xs4[0], m1 = xs4[1];
  const float4* bgp = (const float4*)(bgcn + colb);
  float4 b0 = bgp[0], b1 = bgp[1], b2 = bgp[2], b3 = bgp[3];
  float xv[16];
  unp2(m0.x, xv[0], xv[1]);   unp2(m0.y, xv[2], xv[3]);
  unp2(m0.z, xv[4], xv[5]);   unp2(m0.w, xv[6], xv[7]);
  unp2(m1.x, xv[8], xv[9]);   unp2(m1.y, xv[10], xv[11]);
  unp2(m1.z, xv[12], xv[13]); unp2(m1.w, xv[14], xv[15]);
  float av[16];
  unp2(h22u(acc[0]), av[0], av[1]);   unp2(h22u(acc[1]), av[2], av[3]);
  unp2(h22u(acc[2]), av[4], av[5]);   unp2(h22u(acc[3]), av[6], av[7]);
  unp2(h22u(acc[4]), av[8], av[9]);   unp2(h22u(acc[5]), av[10], av[11]);
  unp2(h22u(acc[6]), av[12], av[13]); unp2(h22u(acc[7]), av[14], av[15]);
  float bgv[16] = {b0.x,b0.y,b0.z,b0.w,b1.x,b1.y,b1.z,b1.w,
                   b2.x,b2.y,b2.z,b2.w,b3.x,b3.y,b3.z,b3.w};
  float ov[16];
#pragma unroll
  for (int j = 0; j < 16; ++j) ov[j] = bgv[j] + dn * av[j] + dn2 * xv[j];
  uint4 o0, o1;
  o0.x = pack2h(ov[0], ov[1]);   o0.y = pack2h(ov[2], ov[3]);
  o0.z = pack2h(ov[4], ov[5]);   o0.w = pack2h(ov[6], ov[7]);
  o1.x = pack2h(ov[8], ov[9]);   o1.y = pack2h(ov[10], ov[11]);
  o1.z = pack2h(ov[12], ov[13]); o1.w = pack2h(ov[14], ov[15]);
  uint4* ob = (uint4*)(feats + (size_t)n * (LE * LN) + l * LN + colb);
  ob[0] = o0; ob[1] = o1;
}

// C[M,NCOL] = A[M,K] @ Bpacked(fp16) (+bias, relu if FIN)
// A fp32 converted in-register (AF32) or fp16; out fp32 or fp16 (OUT16)
template <int K, int NCOL, bool FIN, bool AF32, bool OUT16>
__global__ __launch_bounds__(256) void k_gemm(const void* __restrict__ Av,
    const u16* __restrict__ Bp, const float* __restrict__ bias,
    void* __restrict__ outv, int M) {
  constexpr int NT = NCOL / 16;
  constexpr int KT = K / 32;
  const u16* A16 = (const u16*)Av;
  const float* A32 = (const float*)Av;
  int lane = threadIdx.x & 63;
  int wid = threadIdx.x >> 6;
  int m0 = blockIdx.x * 128 + wid * 32;
  f32x4 acc[2][NT];
#pragma unroll
  for (int mt = 0; mt < 2; ++mt)
#pragma unroll
    for (int nt = 0; nt < NT; ++nt) {
      acc[mt][nt][0] = 0.f; acc[mt][nt][1] = 0.f;
      acc[mt][nt][2] = 0.f; acc[mt][nt][3] = 0.f;
    }
  int r0 = m0 + (lane & 15);
  int r1 = r0 + 16;
  bool v0 = r0 < M, v1 = r1 < M;
  int ko = (lane >> 4) * 8;
#pragma unroll 4
  for (int kt = 0; kt < KT; ++kt) {
    f16x8 a0, a1;
#pragma unroll
    for (int i = 0; i < 8; ++i) { a0[i] = (_Float16)0.f; a1[i] = (_Float16)0.f; }
    if constexpr (AF32) {
      if (v0) {
        const float4* p4 = (const float4*)(A32 + (size_t)r0 * K + ko + kt * 32);
        float4 u0 = p4[0], u1 = p4[1];
        a0[0]=(_Float16)u0.x; a0[1]=(_Float16)u0.y; a0[2]=(_Float16)u0.z; a0[3]=(_Float16)u0.w;
        a0[4]=(_Float16)u1.x; a0[5]=(_Float16)u1.y; a0[6]=(_Float16)u1.z; a0[7]=(_Float16)u1.w;
      }
      if (v1) {
        const float4* p4 = (const float4*)(A32 + (size_t)r1 * K + ko + kt * 32);
        float4 u0 = p4[0], u1 = p4[1];
        a1[0]=(_Float16)u0.x; a1[1]=(_Float16)u0.y; a1[2]=(_Float16)u0.z; a1[3]=(_Float16)u0.w;
        a1[4]=(_Float16)u1.x; a1[5]=(_Float16)u1.y; a1[6]=(_Float16)u1.z; a1[7]=(_Float16)u1.w;
      }
    } else {
      if (v0) a0 = *(const f16x8*)(A16 + (size_t)r0 * K + ko + kt * 32);
      if (v1) a1 = *(const f16x8*)(A16 + (size_t)r1 * K + ko + kt * 32);
    }
#pragma unroll
    for (int nt = 0; nt < NT; ++nt) {
      f16x8 b = *(const f16x8*)(Bp + ((size_t)(nt * KT + kt) * 64 + lane) * 8);
      acc[0][nt] = __builtin_amdgcn_mfma_f32_16x16x32_f16(a0, b, acc[0][nt], 0, 0, 0);
      acc[1][nt] = __builtin_amdgcn_mfma_f32_16x16x32_f16(a1, b, acc[1][nt], 0, 0, 0);
    }
  }
  int col0 = lane & 15;
#pragma unroll
  for (int mt = 0; mt < 2; ++mt) {
    int rb = m0 + mt * 16 + ((lane >> 4) << 2);
#pragma unroll
    for (int nt = 0; nt < NT; ++nt) {
      int c = nt * 16 + col0;
      float bb = FIN ? bias[c] : 0.f;
#pragma unroll
      for (int r = 0; r < 4; ++r) {
        int row = rb + r;
        if (row < M) {
          float vv = acc[mt][nt][r] + bb;
          if (FIN) vv = fmaxf(vv, 0.f);
          if constexpr (OUT16) ((u16*)outv)[(size_t)row * NCOL + c] = f2h(vv);
          else ((float*)outv)[(size_t)row * NCOL + c] = vv;
        }
      }
    }
  }
}

extern "C" void kernel_launch(void* const* d_in, const int* in_sizes, int n_in,
                              void* d_out, int out_size, void* d_ws, size_t ws_size,
                              hipStream_t stream) {
  const float* x  = (const float*)d_in[0];
  const int*   ei = (const int*)d_in[1];
  const float* ea = (const float*)d_in[2];
  const float* Wg = (const float*)d_in[3];
  const float* bg = (const float*)d_in[4];
  const float* We = (const float*)d_in[5];
  const float* be = (const float*)d_in[6];
  const float* Wn = (const float*)d_in[7];
  const float* bn = (const float*)d_in[8];
  float* outp = (float*)d_out;
  int N = in_sizes[0] / DN;  // 50000
  int E = in_sizes[1] / 2;   // 800000

  char* p = (char*)d_ws;
  auto carve = [&](size_t bytes) {
    char* r = p;
    p += (bytes + 255) & ~(size_t)255;
    return (void*)r;
  };
  u16*   wh    = (u16*)carve((size_t)E * LE * 2);    // CSR-ordered latent weights, fp16
  u16*   wsc   = (u16*)carve((size_t)E * LE * 2);    // pre-normalized weights, fp16
  u16*   xwh   = (u16*)carve((size_t)N * LN * 2);    // xW in fp16
  u16*   feats = (u16*)carve((size_t)N * (LE * LN) * 2);  // aggregated feats fp16
  u16*   dinvh = (u16*)carve((size_t)N * LE * 2);    // dinv fp16
  u16*   WnP   = (u16*)carve((size_t)(LE * LN) * DOUT * 2);
  u16*   WgP   = (u16*)carve((size_t)DN * LN * 2);
  int*   offs  = (int*)carve((size_t)(N + 1) * 4);
  int*   cnt   = (int*)carve((size_t)N * 4);
  int*   cur   = (int*)carve((size_t)N * 4);
  int*   src   = (int*)carve((size_t)E * 4);
  int*   eperm = (int*)carve((size_t)E * 4);

  hipMemsetAsync(cnt, 0, (size_t)N * 4, stream);
  hipMemsetAsync(cur, 0, (size_t)N * 4, stream);

  // CSR build
  k_count<<<(E + 255) / 256, 256, 0, stream>>>(ei, cnt, E);
  k_scan<<<1, 1024, 0, stream>>>(cnt, offs, N);
  k_fill<<<(E + 255) / 256, 256, 0, stream>>>(ei, cur, offs, eperm, src, E);
  // edge MLP: gather ea rows in CSR order, coalesced wh write
  k_edge_props<<<(E + 255) / 256, 256, 0, stream>>>(ea, We, be, eperm, wh, E);
  // weight packing (both mats), node GEMM path: xW in fp16
  k_packb2<<<(1024 + 16384 + 255) / 256, 256, 0, stream>>>(Wg, WgP, Wn, WnP);
  k_gemm<DN, LN, false, true, true><<<(N + 127) / 128, 256, 0, stream>>>(x, WgP, nullptr, xwh, N);
  // weighted in-degree normalization (fp16), pre-fold dinv[src] into weights
  k_dinv<<<(N + 15) / 16, 256, 0, stream>>>(wh, offs, dinvh, N);
  k_wsc<<<(E + 255) / 256, 256, 0, stream>>>(wh, src, dinvh, wsc, E);
  // aggregation: ONE wave per node, 16 cols per lane, packed fp16 FMA
  k_feats6<<<(N + 3) / 4, 256, 0, stream>>>(src, wsc, dinvh, xwh, bg, offs, feats, N);
  // output MLP (MFMA, 128-row blocks)
  k_gemm<LE * LN, DOUT, true, false, false><<<(N + 127) / 128, 256, 0, stream>>>(feats, WnP, bn, outp, N);
}

// Round 10
// 382.685 us; speedup vs baseline: 1.3115x; 1.0382x over previous
//
#include <hip/hip_runtime.h>
#include <hip/hip_fp16.h>

typedef _Float16 f16x8 __attribute__((ext_vector_type(8)));
typedef float f32x4 __attribute__((ext_vector_type(4)));
typedef unsigned short u16;

#define DN 128   // node in props
#define DE 32    // edge in props
#define LE 16    // latent edges (channels)
#define LN 64    // latent nodes
#define DOUT 128 // out props

__device__ inline u16 f2h(float f) { return __half_as_ushort(__float2half(f)); }
__device__ inline float h2f(u16 u) { return __half2float(__ushort_as_half(u)); }
__device__ inline unsigned pack2h(float lo, float hi) {
  return (unsigned)f2h(lo) | ((unsigned)f2h(hi) << 16);
}
__device__ inline void unp2(unsigned u, float& a, float& b) {
  __half2 p = *reinterpret_cast<__half2*>(&u);
  a = __half2float(__low2half(p));
  b = __half2float(__high2half(p));
}
__device__ inline __half2 u2h2(unsigned u) {
  return *reinterpret_cast<__half2*>(&u);
}
__device__ inline unsigned h22u(__half2 h) {
  return *reinterpret_cast<unsigned*>(&h);
}

// Pack fp32 W[K,NCOL] into fp16 MFMA-B fragments (both weight mats, one launch)
__device__ inline void packb_one(const float* __restrict__ W, u16* __restrict__ Bp,
                                 int idx, int K, int NCOL) {
  int KT = K >> 5;
  int lane = idx & 63;
  int rest = idx >> 6;
  int kt = rest % KT, nt = rest / KT;
  int col = nt * 16 + (lane & 15);
  int kb = kt * 32 + (lane >> 4) * 8;
  u16* dst = Bp + (size_t)idx * 8;
#pragma unroll
  for (int i = 0; i < 8; ++i) dst[i] = f2h(W[(size_t)(kb + i) * NCOL + col]);
}
__global__ __launch_bounds__(256) void k_packb2(const float* __restrict__ Wg,
    u16* __restrict__ WgP, const float* __restrict__ Wn, u16* __restrict__ WnP) {
  const int totA = (DN / 32) * (LN / 16) * 64;          // 1024
  const int totB = ((LE * LN) / 32) * (DOUT / 16) * 64; // 16384
  int idx = blockIdx.x * 256 + threadIdx.x;
  if (idx < totA) packb_one(Wg, WgP, idx, DN, LN);
  else if (idx < totA + totB) packb_one(Wn, WnP, idx - totA, LE * LN, DOUT);
}

__global__ __launch_bounds__(256) void k_count(const int* __restrict__ ei,
                                               int* __restrict__ cnt, int E) {
  int e = blockIdx.x * 256 + threadIdx.x;
  if (e < E) atomicAdd(&cnt[ei[E + e]], 1);
}

// single-block exclusive scan over cnt[0..N) -> offs[0..N]
__global__ __launch_bounds__(1024) void k_scan(const int* __restrict__ cnt,
                                               int* __restrict__ offs, int N) {
  __shared__ int wsum[16];
  int t = threadIdx.x;
  int chunk = (N + 1023) >> 10;
  int s0 = t * chunk;
  int s1 = min(s0 + chunk, N);
  int s = 0;
  for (int i = s0; i < s1; ++i) s += cnt[i];
  int lane = t & 63, wid = t >> 6;
  int v = s;
#pragma unroll
  for (int d = 1; d < 64; d <<= 1) {
    int u = __shfl_up(v, d);
    if (lane >= d) v += u;
  }
  if (lane == 63) wsum[wid] = v;
  __syncthreads();
  if (t == 0) {
    int run = 0;
    for (int w = 0; w < 16; ++w) { int xv = wsum[w]; wsum[w] = run; run += xv; }
  }
  __syncthreads();
  int run = v - s + wsum[wid];  // exclusive prefix for this thread
  for (int i = s0; i < s1; ++i) { offs[i] = run; run += cnt[i]; }
  if (s1 == N && s0 < N) offs[N] = run;
}

// Fused CSR-fill + edge MLP: streaming ea read, MLP in fp32, scattered CSR write.
// wh[pos,l] = fp16(relu(ea[e,:]@We+be)[l]); src[pos] = ei[e]
__global__ __launch_bounds__(256) void k_fill_mlp(const float* __restrict__ ea,
    const float* __restrict__ We, const float* __restrict__ be,
    const int* __restrict__ ei, int* __restrict__ cur, const int* __restrict__ offs,
    int* __restrict__ src, u16* __restrict__ wh, int E) {
  int e = blockIdx.x * 256 + threadIdx.x;
  if (e >= E) return;
  const float4* a4 = (const float4*)(ea + (size_t)e * DE);
  float a[DE];
#pragma unroll
  for (int j = 0; j < DE / 4; ++j) {
    float4 v = a4[j];
    a[4*j] = v.x; a[4*j+1] = v.y; a[4*j+2] = v.z; a[4*j+3] = v.w;
  }
  float acc[LE];
#pragma unroll
  for (int l = 0; l < LE; ++l) acc[l] = be[l];
#pragma unroll
  for (int k = 0; k < DE; ++k) {
    float av = a[k];
#pragma unroll
    for (int l = 0; l < LE; ++l) acc[l] = fmaf(av, We[k * LE + l], acc[l]);
  }
  uint4 o0, o1;
  o0.x = pack2h(fmaxf(acc[0], 0.f), fmaxf(acc[1], 0.f));
  o0.y = pack2h(fmaxf(acc[2], 0.f), fmaxf(acc[3], 0.f));
  o0.z = pack2h(fmaxf(acc[4], 0.f), fmaxf(acc[5], 0.f));
  o0.w = pack2h(fmaxf(acc[6], 0.f), fmaxf(acc[7], 0.f));
  o1.x = pack2h(fmaxf(acc[8], 0.f), fmaxf(acc[9], 0.f));
  o1.y = pack2h(fmaxf(acc[10], 0.f), fmaxf(acc[11], 0.f));
  o1.z = pack2h(fmaxf(acc[12], 0.f), fmaxf(acc[13], 0.f));
  o1.w = pack2h(fmaxf(acc[14], 0.f), fmaxf(acc[15], 0.f));
  int c = ei[E + e];
  int p = atomicAdd(&cur[c], 1);
  int pos = offs[c] + p;
  src[pos] = ei[e];
  uint4* o4 = (uint4*)(wh + (size_t)pos * LE);
  o4[0] = o0; o4[1] = o1;
}

// dinvh[n,l] = fp16(rsqrt(1 + sum over CSR segment of wh[i,l]))
__global__ __launch_bounds__(256) void k_dinv(const u16* __restrict__ wh,
    const int* __restrict__ offs, u16* __restrict__ dinvh, int N) {
  int t = threadIdx.x;
  int n = blockIdx.x * 16 + (t >> 4);
  int l = t & 15;
  if (n >= N) return;
  int i0 = offs[n], i1 = offs[n + 1];
  float s = 1.0f;  // self loop weight
  for (int i = i0; i < i1; ++i) s += h2f(wh[(size_t)i * LE + l]);
  dinvh[(size_t)n * LE + l] = f2h(rsqrtf(s));
}

// GCN aggregation, ONE wave per node, 4-edge software pipeline, fp16 math.
// lane: l = lane&15 (channel), g = lane>>4; 16 cols/lane.
// coeff folded in-loop: c = wh[pos,l] * dinvh[src,l]  (dinvh is 1.6MB, L2-hot)
__global__ __launch_bounds__(256) void k_feats7(const int* __restrict__ src,
    const u16* __restrict__ wh, const u16* __restrict__ dinvh,
    const u16* __restrict__ xwh, const float* __restrict__ bgcn,
    const int* __restrict__ offs, u16* __restrict__ feats, int N) {
  int wid = threadIdx.x >> 6;
  int n = blockIdx.x * 4 + wid;
  if (n >= N) return;
  int lane = threadIdx.x & 63;
  int l = lane & 15, g = lane >> 4;
  int colb = g * 16;
  const u16* xb = xwh + colb;
  __half2 acc[8];
#pragma unroll
  for (int j = 0; j < 8; ++j) acc[j] = u2h2(0u);
  int i0 = offs[n], i1 = offs[n + 1];
  if (i0 < i1) {
    int rem = i1 - i0;
    int p1 = i0 + (rem > 1 ? 1 : 0);
    int p2 = i0 + (rem > 2 ? 2 : 0);
    int p3 = i0 + (rem > 3 ? 3 : 0);
    int s0 = src[i0], s1 = src[p1], s2 = src[p2], s3 = src[p3];
    for (int i = i0; i < i1; i += 4) {
      rem = i1 - i;
      p1 = i + (rem > 1 ? 1 : 0);
      p2 = i + (rem > 2 ? 2 : 0);
      p3 = i + (rem > 3 ? 3 : 0);
      // issue all coefficient + row loads for 4 edges
      u16 w0 = wh[(size_t)i * LE + l],  w1 = wh[(size_t)p1 * LE + l];
      u16 w2 = wh[(size_t)p2 * LE + l], w3 = wh[(size_t)p3 * LE + l];
      u16 d0 = dinvh[(size_t)s0 * LE + l], d1 = dinvh[(size_t)s1 * LE + l];
      u16 d2 = dinvh[(size_t)s2 * LE + l], d3 = dinvh[(size_t)s3 * LE + l];
      const uint4* q0 = (const uint4*)(xb + (size_t)s0 * LN);
      const uint4* q1 = (const uint4*)(xb + (size_t)s1 * LN);
      const uint4* q2 = (const uint4*)(xb + (size_t)s2 * LN);
      const uint4* q3 = (const uint4*)(xb + (size_t)s3 * LN);
      uint4 r0a = q0[0], r0b = q0[1];
      uint4 r1a = q1[0], r1b = q1[1];
      uint4 r2a = q2[0], r2b = q2[1];
      uint4 r3a = q3[0], r3b = q3[1];
      // prefetch next group's src while rows are in flight
      int inx = i + 4;
      if (inx < i1) {
        int r2_ = i1 - inx;
        int n1 = inx + (r2_ > 1 ? 1 : 0);
        int n2 = inx + (r2_ > 2 ? 2 : 0);
        int n3 = inx + (r2_ > 3 ? 3 : 0);
        s0 = src[inx]; s1 = src[n1]; s2 = src[n2]; s3 = src[n3];
      }
      // coefficients (fp16 mul), dummies zeroed
      unsigned c0u = (unsigned)__half_as_ushort(
          __hmul(__ushort_as_half(w0), __ushort_as_half(d0)));
      unsigned c1u = (unsigned)__half_as_ushort(
          __hmul(__ushort_as_half(w1), __ushort_as_half(d1)));
      unsigned c2u = (unsigned)__half_as_ushort(
          __hmul(__ushort_as_half(w2), __ushort_as_half(d2)));
      unsigned c3u = (unsigned)__half_as_ushort(
          __hmul(__ushort_as_half(w3), __ushort_as_half(d3)));
      if (rem < 2) c1u = 0u;
      if (rem < 3) c2u = 0u;
      if (rem < 4) c3u = 0u;
      __half2 c0 = u2h2(c0u | (c0u << 16));
      __half2 c1 = u2h2(c1u | (c1u << 16));
      __half2 c2 = u2h2(c2u | (c2u << 16));
      __half2 c3 = u2h2(c3u | (c3u << 16));
      acc[0] = __hfma2(c0, u2h2(r0a.x), acc[0]);
      acc[1] = __hfma2(c0, u2h2(r0a.y), acc[1]);
      acc[2] = __hfma2(c0, u2h2(r0a.z), acc[2]);
      acc[3] = __hfma2(c0, u2h2(r0a.w), acc[3]);
      acc[4] = __hfma2(c0, u2h2(r0b.x), acc[4]);
      acc[5] = __hfma2(c0, u2h2(r0b.y), acc[5]);
      acc[6] = __hfma2(c0, u2h2(r0b.z), acc[6]);
      acc[7] = __hfma2(c0, u2h2(r0b.w), acc[7]);
      acc[0] = __hfma2(c1, u2h2(r1a.x), acc[0]);
      acc[1] = __hfma2(c1, u2h2(r1a.y), acc[1]);
      acc[2] = __hfma2(c1, u2h2(r1a.z), acc[2]);
      acc[3] = __hfma2(c1, u2h2(r1a.w), acc[3]);
      acc[4] = __hfma2(c1, u2h2(r1b.x), acc[4]);
      acc[5] = __hfma2(c1, u2h2(r1b.y), acc[5]);
      acc[6] = __hfma2(c1, u2h2(r1b.z), acc[6]);
      acc[7] = __hfma2(c1, u2h2(r1b.w), acc[7]);
      acc[0] = __hfma2(c2, u2h2(r2a.x), acc[0]);
      acc[1] = __hfma2(c2, u2h2(r2a.y), acc[1]);
      acc[2] = __hfma2(c2, u2h2(r2a.z), acc[2]);
      acc[3] = __hfma2(c2, u2h2(r2a.w), acc[3]);
      acc[4] = __hfma2(c2, u2h2(r2b.x), acc[4]);
      acc[5] = __hfma2(c2, u2h2(r2b.y), acc[5]);
      acc[6] = __hfma2(c2, u2h2(r2b.z), acc[6]);
      acc[7] = __hfma2(c2, u2h2(r2b.w), acc[7]);
      acc[0] = __hfma2(c3, u2h2(r3a.x), acc[0]);
      acc[1] = __hfma2(c3, u2h2(r3a.y), acc[1]);
      acc[2] = __hfma2(c3, u2h2(r3a.z), acc[2]);
      acc[3] = __hfma2(c3, u2h2(r3a.w), acc[3]);
      acc[4] = __hfma2(c3, u2h2(r3b.x), acc[4]);
      acc[5] = __hfma2(c3, u2h2(r3b.y), acc[5]);
      acc[6] = __hfma2(c3, u2h2(r3b.z), acc[6]);
      acc[7] = __hfma2(c3, u2h2(r3b.w), acc[7]);
    }
  }
  float dn = h2f(dinvh[(size_t)n * LE + l]);
  float dn2 = dn * dn;
  const uint4* xs4 = (const uint4*)(xwh + (size_t)n * LN + colb);
  uint4 m0 = xs4[0], m1 = xs4[1];
  const float4* bgp = (const float4*)(bgcn + colb);
  float4 b0 = bgp[0], b1 = bgp[1], b2 = bgp[2], b3 = bgp[3];
  float xv[16];
  unp2(m0.x, xv[0], xv[1]);   unp2(m0.y, xv[2], xv[3]);
  unp2(m0.z, xv[4], xv[5]);   unp2(m0.w, xv[6], xv[7]);
  unp2(m1.x, xv[8], xv[9]);   unp2(m1.y, xv[10], xv[11]);
  unp2(m1.z, xv[12], xv[13]); unp2(m1.w, xv[14], xv[15]);
  float av[16];
  unp2(h22u(acc[0]), av[0], av[1]);   unp2(h22u(acc[1]), av[2], av[3]);
  unp2(h22u(acc[2]), av[4], av[5]);   unp2(h22u(acc[3]), av[6], av[7]);
  unp2(h22u(acc[4]), av[8], av[9]);   unp2(h22u(acc[5]), av[10], av[11]);
  unp2(h22u(acc[6]), av[12], av[13]); unp2(h22u(acc[7]), av[14], av[15]);
  float bgv[16] = {b0.x,b0.y,b0.z,b0.w,b1.x,b1.y,b1.z,b1.w,
                   b2.x,b2.y,b2.z,b2.w,b3.x,b3.y,b3.z,b3.w};
  float ov[16];
#pragma unroll
  for (int j = 0; j < 16; ++j) ov[j] = bgv[j] + dn * av[j] + dn2 * xv[j];
  uint4 o0, o1;
  o0.x = pack2h(ov[0], ov[1]);   o0.y = pack2h(ov[2], ov[3]);
  o0.z = pack2h(ov[4], ov[5]);   o0.w = pack2h(ov[6], ov[7]);
  o1.x = pack2h(ov[8], ov[9]);   o1.y = pack2h(ov[10], ov[11]);
  o1.z = pack2h(ov[12], ov[13]); o1.w = pack2h(ov[14], ov[15]);
  uint4* ob = (uint4*)(feats + (size_t)n * (LE * LN) + l * LN + colb);
  ob[0] = o0; ob[1] = o1;
}

// C[M,NCOL] = A[M,K] @ Bpacked(fp16) (+bias, relu if FIN)
template <int K, int NCOL, bool FIN, bool AF32, bool OUT16>
__global__ __launch_bounds__(256) void k_gemm(const void* __restrict__ Av,
    const u16* __restrict__ Bp, const float* __restrict__ bias,
    void* __restrict__ outv, int M) {
  constexpr int NT = NCOL / 16;
  constexpr int KT = K / 32;
  const u16* A16 = (const u16*)Av;
  const float* A32 = (const float*)Av;
  int lane = threadIdx.x & 63;
  int wid = threadIdx.x >> 6;
  int m0 = blockIdx.x * 128 + wid * 32;
  f32x4 acc[2][NT];
#pragma unroll
  for (int mt = 0; mt < 2; ++mt)
#pragma unroll
    for (int nt = 0; nt < NT; ++nt) {
      acc[mt][nt][0] = 0.f; acc[mt][nt][1] = 0.f;
      acc[mt][nt][2] = 0.f; acc[mt][nt][3] = 0.f;
    }
  int r0 = m0 + (lane & 15);
  int r1 = r0 + 16;
  bool v0 = r0 < M, v1 = r1 < M;
  int ko = (lane >> 4) * 8;
#pragma unroll 4
  for (int kt = 0; kt < KT; ++kt) {
    f16x8 a0, a1;
#pragma unroll
    for (int i = 0; i < 8; ++i) { a0[i] = (_Float16)0.f; a1[i] = (_Float16)0.f; }
    if constexpr (AF32) {
      if (v0) {
        const float4* p4 = (const float4*)(A32 + (size_t)r0 * K + ko + kt * 32);
        float4 u0 = p4[0], u1 = p4[1];
        a0[0]=(_Float16)u0.x; a0[1]=(_Float16)u0.y; a0[2]=(_Float16)u0.z; a0[3]=(_Float16)u0.w;
        a0[4]=(_Float16)u1.x; a0[5]=(_Float16)u1.y; a0[6]=(_Float16)u1.z; a0[7]=(_Float16)u1.w;
      }
      if (v1) {
        const float4* p4 = (const float4*)(A32 + (size_t)r1 * K + ko + kt * 32);
        float4 u0 = p4[0], u1 = p4[1];
        a1[0]=(_Float16)u0.x; a1[1]=(_Float16)u0.y; a1[2]=(_Float16)u0.z; a1[3]=(_Float16)u0.w;
        a1[4]=(_Float16)u1.x; a1[5]=(_Float16)u1.y; a1[6]=(_Float16)u1.z; a1[7]=(_Float16)u1.w;
      }
    } else {
      if (v0) a0 = *(const f16x8*)(A16 + (size_t)r0 * K + ko + kt * 32);
      if (v1) a1 = *(const f16x8*)(A16 + (size_t)r1 * K + ko + kt * 32);
    }
#pragma unroll
    for (int nt = 0; nt < NT; ++nt) {
      f16x8 b = *(const f16x8*)(Bp + ((size_t)(nt * KT + kt) * 64 + lane) * 8);
      acc[0][nt] = __builtin_amdgcn_mfma_f32_16x16x32_f16(a0, b, acc[0][nt], 0, 0, 0);
      acc[1][nt] = __builtin_amdgcn_mfma_f32_16x16x32_f16(a1, b, acc[1][nt], 0, 0, 0);
    }
  }
  int col0 = lane & 15;
#pragma unroll
  for (int mt = 0; mt < 2; ++mt) {
    int rb = m0 + mt * 16 + ((lane >> 4) << 2);
#pragma unroll
    for (int nt = 0; nt < NT; ++nt) {
      int c = nt * 16 + col0;
      float bb = FIN ? bias[c] : 0.f;
#pragma unroll
      for (int r = 0; r < 4; ++r) {
        int row = rb + r;
        if (row < M) {
          float vv = acc[mt][nt][r] + bb;
          if (FIN) vv = fmaxf(vv, 0.f);
          if constexpr (OUT16) ((u16*)outv)[(size_t)row * NCOL + c] = f2h(vv);
          else ((float*)outv)[(size_t)row * NCOL + c] = vv;
        }
      }
    }
  }
}

extern "C" void kernel_launch(void* const* d_in, const int* in_sizes, int n_in,
                              void* d_out, int out_size, void* d_ws, size_t ws_size,
                              hipStream_t stream) {
  const float* x  = (const float*)d_in[0];
  const int*   ei = (const int*)d_in[1];
  const float* ea = (const float*)d_in[2];
  const float* Wg = (const float*)d_in[3];
  const float* bg = (const float*)d_in[4];
  const float* We = (const float*)d_in[5];
  const float* be = (const float*)d_in[6];
  const float* Wn = (const float*)d_in[7];
  const float* bn = (const float*)d_in[8];
  float* outp = (float*)d_out;
  int N = in_sizes[0] / DN;  // 50000
  int E = in_sizes[1] / 2;   // 800000

  char* p = (char*)d_ws;
  auto carve = [&](size_t bytes) {
    char* r = p;
    p += (bytes + 255) & ~(size_t)255;
    return (void*)r;
  };
  u16*   wh    = (u16*)carve((size_t)E * LE * 2);    // CSR-ordered latent weights, fp16
  u16*   xwh   = (u16*)carve((size_t)N * LN * 2);    // xW in fp16
  u16*   feats = (u16*)carve((size_t)N * (LE * LN) * 2);  // aggregated feats fp16
  u16*   dinvh = (u16*)carve((size_t)N * LE * 2);    // dinv fp16
  u16*   WnP   = (u16*)carve((size_t)(LE * LN) * DOUT * 2);
  u16*   WgP   = (u16*)carve((size_t)DN * LN * 2);
  int*   offs  = (int*)carve((size_t)(N + 1) * 4);
  int*   cnt   = (int*)carve((size_t)N * 4);
  int*   cur   = (int*)carve((size_t)N * 4);
  int*   src   = (int*)carve((size_t)E * 4);

  hipMemsetAsync(cnt, 0, (size_t)N * 4, stream);
  hipMemsetAsync(cur, 0, (size_t)N * 4, stream);

  // CSR build: count + scan, then fused fill+edge-MLP (streaming ea read)
  k_count<<<(E + 255) / 256, 256, 0, stream>>>(ei, cnt, E);
  k_scan<<<1, 1024, 0, stream>>>(cnt, offs, N);
  k_fill_mlp<<<(E + 255) / 256, 256, 0, stream>>>(ea, We, be, ei, cur, offs, src, wh, E);
  // weight packing (both mats), node GEMM path: xW in fp16
  k_packb2<<<(1024 + 16384 + 255) / 256, 256, 0, stream>>>(Wg, WgP, Wn, WnP);
  k_gemm<DN, LN, false, true, true><<<(N + 127) / 128, 256, 0, stream>>>(x, WgP, nullptr, xwh, N);
  // weighted in-degree normalization (fp16)
  k_dinv<<<(N + 15) / 16, 256, 0, stream>>>(wh, offs, dinvh, N);
  // aggregation: ONE wave per node, 4-edge pipeline, dinvh[src] folded in-loop
  k_feats7<<<(N + 3) / 4, 256, 0, stream>>>(src, wh, dinvh, xwh, bg, offs, feats, N);
  // output MLP (MFMA, 128-row blocks)
  k_gemm<LE * LN, DOUT, true, false, false><<<(N + 127) / 128, 256, 0, stream>>>(feats, WnP, bn, outp, N);
}

// Round 11
// 367.829 us; speedup vs baseline: 1.3645x; 1.0404x over previous
//
#include <hip/hip_runtime.h>
#include <hip/hip_fp16.h>

typedef _Float16 f16x8 __attribute__((ext_vector_type(8)));
typedef float f32x4 __attribute__((ext_vector_type(4)));
typedef unsigned short u16;

#define DN 128   // node in props
#define DE 32    // edge in props
#define LE 16    // latent edges (channels)
#define LN 64    // latent nodes
#define DOUT 128 // out props

__device__ inline u16 f2h(float f) { return __half_as_ushort(__float2half(f)); }
__device__ inline float h2f(u16 u) { return __half2float(__ushort_as_half(u)); }
__device__ inline unsigned pack2h(float lo, float hi) {
  return (unsigned)f2h(lo) | ((unsigned)f2h(hi) << 16);
}
__device__ inline void unp2(unsigned u, float& a, float& b) {
  __half2 p = *reinterpret_cast<__half2*>(&u);
  a = __half2float(__low2half(p));
  b = __half2float(__high2half(p));
}
__device__ inline __half2 u2h2(unsigned u) {
  return *reinterpret_cast<__half2*>(&u);
}
__device__ inline unsigned h22u(__half2 h) {
  return *reinterpret_cast<unsigned*>(&h);
}

// ---------------- weight packing (device body) ----------------
__device__ inline void packb_one(const float* __restrict__ W, u16* __restrict__ Bp,
                                 int idx, int K, int NCOL) {
  int KT = K >> 5;
  int lane = idx & 63;
  int rest = idx >> 6;
  int kt = rest % KT, nt = rest / KT;
  int col = nt * 16 + (lane & 15);
  int kb = kt * 32 + (lane >> 4) * 8;
  u16* dst = Bp + (size_t)idx * 8;
#pragma unroll
  for (int i = 0; i < 8; ++i) dst[i] = f2h(W[(size_t)(kb + i) * NCOL + col]);
}

__global__ __launch_bounds__(256) void k_count(const int* __restrict__ ei,
                                               int* __restrict__ cnt, int E) {
  int e = blockIdx.x * 256 + threadIdx.x;
  if (e < E) atomicAdd(&cnt[ei[E + e]], 1);
}

// block 0: single-block exclusive scan cnt->offs; blocks >=1: pack both weight mats
__global__ __launch_bounds__(1024) void k_scan_packb(const int* __restrict__ cnt,
    int* __restrict__ offs, int N,
    const float* __restrict__ Wg, u16* __restrict__ WgP,
    const float* __restrict__ Wn, u16* __restrict__ WnP) {
  const int totA = (DN / 32) * (LN / 16) * 64;          // 1024
  const int totB = ((LE * LN) / 32) * (DOUT / 16) * 64; // 16384
  if (blockIdx.x != 0) {
    int idx = (blockIdx.x - 1) * 1024 + threadIdx.x;
    if (idx < totA) packb_one(Wg, WgP, idx, DN, LN);
    else if (idx < totA + totB) packb_one(Wn, WnP, idx - totA, LE * LN, DOUT);
    return;
  }
  __shared__ int wsum[16];
  int t = threadIdx.x;
  int chunk = (N + 1023) >> 10;
  int s0 = t * chunk;
  int s1 = min(s0 + chunk, N);
  int s = 0;
  for (int i = s0; i < s1; ++i) s += cnt[i];
  int lane = t & 63, wid = t >> 6;
  int v = s;
#pragma unroll
  for (int d = 1; d < 64; d <<= 1) {
    int u = __shfl_up(v, d);
    if (lane >= d) v += u;
  }
  if (lane == 63) wsum[wid] = v;
  __syncthreads();
  if (t == 0) {
    int run = 0;
    for (int w = 0; w < 16; ++w) { int xv = wsum[w]; wsum[w] = run; run += xv; }
  }
  __syncthreads();
  int run = v - s + wsum[wid];  // exclusive prefix for this thread
  for (int i = s0; i < s1; ++i) { offs[i] = run; run += cnt[i]; }
  if (s1 == N && s0 < N) offs[N] = run;
}

// Fused CSR-fill + edge MLP: streaming ea read, MLP in fp32, scattered CSR write.
// wh[pos,l] = fp16(relu(ea[e,:]@We+be)[l]); src[pos] = ei[e]
__global__ __launch_bounds__(256) void k_fill_mlp(const float* __restrict__ ea,
    const float* __restrict__ We, const float* __restrict__ be,
    const int* __restrict__ ei, int* __restrict__ cur, const int* __restrict__ offs,
    int* __restrict__ src, u16* __restrict__ wh, int E) {
  int e = blockIdx.x * 256 + threadIdx.x;
  if (e >= E) return;
  const float4* a4 = (const float4*)(ea + (size_t)e * DE);
  float a[DE];
#pragma unroll
  for (int j = 0; j < DE / 4; ++j) {
    float4 v = a4[j];
    a[4*j] = v.x; a[4*j+1] = v.y; a[4*j+2] = v.z; a[4*j+3] = v.w;
  }
  float acc[LE];
#pragma unroll
  for (int l = 0; l < LE; ++l) acc[l] = be[l];
#pragma unroll
  for (int k = 0; k < DE; ++k) {
    float av = a[k];
#pragma unroll
    for (int l = 0; l < LE; ++l) acc[l] = fmaf(av, We[k * LE + l], acc[l]);
  }
  uint4 o0, o1;
  o0.x = pack2h(fmaxf(acc[0], 0.f), fmaxf(acc[1], 0.f));
  o0.y = pack2h(fmaxf(acc[2], 0.f), fmaxf(acc[3], 0.f));
  o0.z = pack2h(fmaxf(acc[4], 0.f), fmaxf(acc[5], 0.f));
  o0.w = pack2h(fmaxf(acc[6], 0.f), fmaxf(acc[7], 0.f));
  o1.x = pack2h(fmaxf(acc[8], 0.f), fmaxf(acc[9], 0.f));
  o1.y = pack2h(fmaxf(acc[10], 0.f), fmaxf(acc[11], 0.f));
  o1.z = pack2h(fmaxf(acc[12], 0.f), fmaxf(acc[13], 0.f));
  o1.w = pack2h(fmaxf(acc[14], 0.f), fmaxf(acc[15], 0.f));
  int c = ei[E + e];
  int p = atomicAdd(&cur[c], 1);
  int pos = offs[c] + p;
  src[pos] = ei[e];
  uint4* o4 = (uint4*)(wh + (size_t)pos * LE);
  o4[0] = o0; o4[1] = o1;
}

// ---------------- GEMM body (shared by gemm2 kernel and merged dinv+gemm1) ----
template <int K, int NCOL, bool FIN, bool AF32, bool OUT16>
__device__ inline void gemm_body(int bid, const void* __restrict__ Av,
    const u16* __restrict__ Bp, const float* __restrict__ bias,
    void* __restrict__ outv, int M) {
  constexpr int NT = NCOL / 16;
  constexpr int KT = K / 32;
  const u16* A16 = (const u16*)Av;
  const float* A32 = (const float*)Av;
  int lane = threadIdx.x & 63;
  int wid = threadIdx.x >> 6;
  int m0 = bid * 128 + wid * 32;
  f32x4 acc[2][NT];
#pragma unroll
  for (int mt = 0; mt < 2; ++mt)
#pragma unroll
    for (int nt = 0; nt < NT; ++nt) {
      acc[mt][nt][0] = 0.f; acc[mt][nt][1] = 0.f;
      acc[mt][nt][2] = 0.f; acc[mt][nt][3] = 0.f;
    }
  int r0 = m0 + (lane & 15);
  int r1 = r0 + 16;
  bool v0 = r0 < M, v1 = r1 < M;
  int ko = (lane >> 4) * 8;
#pragma unroll 4
  for (int kt = 0; kt < KT; ++kt) {
    f16x8 a0, a1;
#pragma unroll
    for (int i = 0; i < 8; ++i) { a0[i] = (_Float16)0.f; a1[i] = (_Float16)0.f; }
    if constexpr (AF32) {
      if (v0) {
        const float4* p4 = (const float4*)(A32 + (size_t)r0 * K + ko + kt * 32);
        float4 u0 = p4[0], u1 = p4[1];
        a0[0]=(_Float16)u0.x; a0[1]=(_Float16)u0.y; a0[2]=(_Float16)u0.z; a0[3]=(_Float16)u0.w;
        a0[4]=(_Float16)u1.x; a0[5]=(_Float16)u1.y; a0[6]=(_Float16)u1.z; a0[7]=(_Float16)u1.w;
      }
      if (v1) {
        const float4* p4 = (const float4*)(A32 + (size_t)r1 * K + ko + kt * 32);
        float4 u0 = p4[0], u1 = p4[1];
        a1[0]=(_Float16)u0.x; a1[1]=(_Float16)u0.y; a1[2]=(_Float16)u0.z; a1[3]=(_Float16)u0.w;
        a1[4]=(_Float16)u1.x; a1[5]=(_Float16)u1.y; a1[6]=(_Float16)u1.z; a1[7]=(_Float16)u1.w;
      }
    } else {
      if (v0) a0 = *(const f16x8*)(A16 + (size_t)r0 * K + ko + kt * 32);
      if (v1) a1 = *(const f16x8*)(A16 + (size_t)r1 * K + ko + kt * 32);
    }
#pragma unroll
    for (int nt = 0; nt < NT; ++nt) {
      f16x8 b = *(const f16x8*)(Bp + ((size_t)(nt * KT + kt) * 64 + lane) * 8);
      acc[0][nt] = __builtin_amdgcn_mfma_f32_16x16x32_f16(a0, b, acc[0][nt], 0, 0, 0);
      acc[1][nt] = __builtin_amdgcn_mfma_f32_16x16x32_f16(a1, b, acc[1][nt], 0, 0, 0);
    }
  }
  int col0 = lane & 15;
#pragma unroll
  for (int mt = 0; mt < 2; ++mt) {
    int rb = m0 + mt * 16 + ((lane >> 4) << 2);
#pragma unroll
    for (int nt = 0; nt < NT; ++nt) {
      int c = nt * 16 + col0;
      float bb = FIN ? bias[c] : 0.f;
#pragma unroll
      for (int r = 0; r < 4; ++r) {
        int row = rb + r;
        if (row < M) {
          float vv = acc[mt][nt][r] + bb;
          if (FIN) vv = fmaxf(vv, 0.f);
          if constexpr (OUT16) ((u16*)outv)[(size_t)row * NCOL + c] = f2h(vv);
          else ((float*)outv)[(size_t)row * NCOL + c] = vv;
        }
      }
    }
  }
}

// blocks [0,DB): dinvh[n,l] = fp16(rsqrt(1+seg-sum of wh));
// blocks [DB,DB+GB): gemm1 xwh = fp16(x @ Wg)
__global__ __launch_bounds__(256) void k_dinv_gemm1(const u16* __restrict__ wh,
    const int* __restrict__ offs, u16* __restrict__ dinvh, int N, int DB,
    const float* __restrict__ x, const u16* __restrict__ WgP, u16* __restrict__ xwh) {
  if ((int)blockIdx.x >= DB) {
    gemm_body<DN, LN, false, true, true>(blockIdx.x - DB, x, WgP, nullptr, xwh, N);
    return;
  }
  int t = threadIdx.x;
  int n = blockIdx.x * 16 + (t >> 4);
  int l = t & 15;
  if (n >= N) return;
  int i0 = offs[n], i1 = offs[n + 1];
  float s = 1.0f;  // self loop weight
  for (int i = i0; i < i1; ++i) s += h2f(wh[(size_t)i * LE + l]);
  dinvh[(size_t)n * LE + l] = f2h(rsqrtf(s));
}

// GCN aggregation, ONE wave per node, 2-edge unroll (round-9 structure: low VGPR,
// high occupancy beats deeper pipelines here — verified twice, r3 & r10),
// dinvh[src] folded in-loop. lane: l = lane&15 (channel), g = lane>>4; 16 cols/lane.
__global__ __launch_bounds__(256) void k_feats8(const int* __restrict__ src,
    const u16* __restrict__ wh, const u16* __restrict__ dinvh,
    const u16* __restrict__ xwh, const float* __restrict__ bgcn,
    const int* __restrict__ offs, u16* __restrict__ feats, int N) {
  int wid = threadIdx.x >> 6;
  int n = blockIdx.x * 4 + wid;
  if (n >= N) return;
  int lane = threadIdx.x & 63;
  int l = lane & 15, g = lane >> 4;
  int colb = g * 16;
  const u16* xb = xwh + colb;
  __half2 acc[8];
#pragma unroll
  for (int j = 0; j < 8; ++j) acc[j] = u2h2(0u);
  int i0 = offs[n], i1 = offs[n + 1];
  int sA = (i0 < i1) ? src[i0] : 0;
  for (int i = i0; i < i1; i += 2) {
    bool two = (i + 1 < i1);
    int s0 = sA;
    int s1 = two ? src[i + 1] : s0;
    u16 w0 = wh[(size_t)i * LE + l];
    u16 w1 = two ? wh[(size_t)(i + 1) * LE + l] : (u16)0;
    u16 d0 = dinvh[(size_t)s0 * LE + l];
    u16 d1 = dinvh[(size_t)s1 * LE + l];
    const uint4* p0 = (const uint4*)(xb + (size_t)s0 * LN);
    const uint4* p1 = (const uint4*)(xb + (size_t)s1 * LN);
    uint4 r0a = p0[0], r0b = p0[1];
    uint4 r1a = p1[0], r1b = p1[1];
    if (i + 2 < i1) sA = src[i + 2];
    unsigned c0u = (unsigned)__half_as_ushort(
        __hmul(__ushort_as_half(w0), __ushort_as_half(d0)));
    unsigned c1u = (unsigned)__half_as_ushort(
        __hmul(__ushort_as_half(w1), __ushort_as_half(d1)));  // w1=0 -> c1=0
    __half2 c02 = u2h2(c0u | (c0u << 16));
    __half2 c12 = u2h2(c1u | (c1u << 16));
    acc[0] = __hfma2(c02, u2h2(r0a.x), acc[0]);
    acc[1] = __hfma2(c02, u2h2(r0a.y), acc[1]);
    acc[2] = __hfma2(c02, u2h2(r0a.z), acc[2]);
    acc[3] = __hfma2(c02, u2h2(r0a.w), acc[3]);
    acc[4] = __hfma2(c02, u2h2(r0b.x), acc[4]);
    acc[5] = __hfma2(c02, u2h2(r0b.y), acc[5]);
    acc[6] = __hfma2(c02, u2h2(r0b.z), acc[6]);
    acc[7] = __hfma2(c02, u2h2(r0b.w), acc[7]);
    acc[0] = __hfma2(c12, u2h2(r1a.x), acc[0]);
    acc[1] = __hfma2(c12, u2h2(r1a.y), acc[1]);
    acc[2] = __hfma2(c12, u2h2(r1a.z), acc[2]);
    acc[3] = __hfma2(c12, u2h2(r1a.w), acc[3]);
    acc[4] = __hfma2(c12, u2h2(r1b.x), acc[4]);
    acc[5] = __hfma2(c12, u2h2(r1b.y), acc[5]);
    acc[6] = __hfma2(c12, u2h2(r1b.z), acc[6]);
    acc[7] = __hfma2(c12, u2h2(r1b.w), acc[7]);
  }
  float dn = h2f(dinvh[(size_t)n * LE + l]);
  float dn2 = dn * dn;
  const uint4* xs4 = (const uint4*)(xwh + (size_t)n * LN + colb);
  uint4 m0 = xs4[0], m1 = xs4[1];
  const float4* bgp = (const float4*)(bgcn + colb);
  float4 b0 = bgp[0], b1 = bgp[1], b2 = bgp[2], b3 = bgp[3];
  float xv[16];
  unp2(m0.x, xv[0], xv[1]);   unp2(m0.y, xv[2], xv[3]);
  unp2(m0.z, xv[4], xv[5]);   unp2(m0.w, xv[6], xv[7]);
  unp2(m1.x, xv[8], xv[9]);   unp2(m1.y, xv[10], xv[11]);
  unp2(m1.z, xv[12], xv[13]); unp2(m1.w, xv[14], xv[15]);
  float av[16];
  unp2(h22u(acc[0]), av[0], av[1]);   unp2(h22u(acc[1]), av[2], av[3]);
  unp2(h22u(acc[2]), av[4], av[5]);   unp2(h22u(acc[3]), av[6], av[7]);
  unp2(h22u(acc[4]), av[8], av[9]);   unp2(h22u(acc[5]), av[10], av[11]);
  unp2(h22u(acc[6]), av[12], av[13]); unp2(h22u(acc[7]), av[14], av[15]);
  float bgv[16] = {b0.x,b0.y,b0.z,b0.w,b1.x,b1.y,b1.z,b1.w,
                   b2.x,b2.y,b2.z,b2.w,b3.x,b3.y,b3.z,b3.w};
  float ov[16];
#pragma unroll
  for (int j = 0; j < 16; ++j) ov[j] = bgv[j] + dn * av[j] + dn2 * xv[j];
  uint4 o0, o1;
  o0.x = pack2h(ov[0], ov[1]);   o0.y = pack2h(ov[2], ov[3]);
  o0.z = pack2h(ov[4], ov[5]);   o0.w = pack2h(ov[6], ov[7]);
  o1.x = pack2h(ov[8], ov[9]);   o1.y = pack2h(ov[10], ov[11]);
  o1.z = pack2h(ov[12], ov[13]); o1.w = pack2h(ov[14], ov[15]);
  uint4* ob = (uint4*)(feats + (size_t)n * (LE * LN) + l * LN + colb);
  ob[0] = o0; ob[1] = o1;
}

// standalone gemm (used for output MLP)
template <int K, int NCOL, bool FIN, bool AF32, bool OUT16>
__global__ __launch_bounds__(256) void k_gemm(const void* __restrict__ Av,
    const u16* __restrict__ Bp, const float* __restrict__ bias,
    void* __restrict__ outv, int M) {
  gemm_body<K, NCOL, FIN, AF32, OUT16>(blockIdx.x, Av, Bp, bias, outv, M);
}

extern "C" void kernel_launch(void* const* d_in, const int* in_sizes, int n_in,
                              void* d_out, int out_size, void* d_ws, size_t ws_size,
                              hipStream_t stream) {
  const float* x  = (const float*)d_in[0];
  const int*   ei = (const int*)d_in[1];
  const float* ea = (const float*)d_in[2];
  const float* Wg = (const float*)d_in[3];
  const float* bg = (const float*)d_in[4];
  const float* We = (const float*)d_in[5];
  const float* be = (const float*)d_in[6];
  const float* Wn = (const float*)d_in[7];
  const float* bn = (const float*)d_in[8];
  float* outp = (float*)d_out;
  int N = in_sizes[0] / DN;  // 50000
  int E = in_sizes[1] / 2;   // 800000

  char* p = (char*)d_ws;
  auto carve = [&](size_t bytes) {
    char* r = p;
    p += (bytes + 255) & ~(size_t)255;
    return (void*)r;
  };
  size_t npad = ((size_t)N * 4 + 255) & ~(size_t)255;
  u16*   wh    = (u16*)carve((size_t)E * LE * 2);    // CSR-ordered latent weights, fp16
  u16*   xwh   = (u16*)carve((size_t)N * LN * 2);    // xW in fp16
  u16*   feats = (u16*)carve((size_t)N * (LE * LN) * 2);  // aggregated feats fp16
  u16*   dinvh = (u16*)carve((size_t)N * LE * 2);    // dinv fp16
  u16*   WnP   = (u16*)carve((size_t)(LE * LN) * DOUT * 2);
  u16*   WgP   = (u16*)carve((size_t)DN * LN * 2);
  int*   offs  = (int*)carve((size_t)(N + 1) * 4);
  int*   cnt   = (int*)carve(2 * npad);              // cnt + cur contiguous
  int*   cur   = (int*)((char*)cnt + npad);
  int*   src   = (int*)carve((size_t)E * 4);

  hipMemsetAsync(cnt, 0, 2 * npad, stream);

  // CSR histogram
  k_count<<<(E + 255) / 256, 256, 0, stream>>>(ei, cnt, E);
  // scan (block 0) + pack both weight matrices (blocks 1..17)
  k_scan_packb<<<18, 1024, 0, stream>>>(cnt, offs, N, Wg, WgP, Wn, WnP);
  // fused CSR-fill + edge MLP (streaming ea read, scattered CSR write)
  k_fill_mlp<<<(E + 255) / 256, 256, 0, stream>>>(ea, We, be, ei, cur, offs, src, wh, E);
  // dinv (blocks [0,DB)) + gemm1 x@Wg -> xwh fp16 (blocks [DB,DB+GB))
  int DB = (N + 15) / 16, GB = (N + 127) / 128;
  k_dinv_gemm1<<<DB + GB, 256, 0, stream>>>(wh, offs, dinvh, N, DB, x, WgP, xwh);
  // aggregation: ONE wave per node, 2-edge unroll, dinvh[src] folded in-loop
  k_feats8<<<(N + 3) / 4, 256, 0, stream>>>(src, wh, dinvh, xwh, bg, offs, feats, N);
  // output MLP (MFMA, 128-row blocks)
  k_gemm<LE * LN, DOUT, true, false, false><<<(N + 127) / 128, 256, 0, stream>>>(feats, WnP, bn, outp, N);
}